// Round 7
// baseline (668.402 us; speedup 1.0000x reference)
//
#include <hip/hip_runtime.h>
#include <cstdint>
#include <cstddef>

// PCFG inside algorithm. B=8, n=28, NT=32, T=64, ST=96.
// Persistent cooperative kernel: grid = B*10 blocks, 512 threads.
// Block (b,ch) owns 512 pair-columns of the packed erule table in REGISTERS.
// Per width: finalize prev width from chunk partials (redundant per block,
// bitwise identical), build numer for own chunk, contract, write partials,
// then per-batch 10-block barrier via one monotone agent-scope counter.
// ALL cross-block data (partials, eB rows) uses agent-scope atomic
// load/store (cache-bypass to the device coherence point) -> no L2 flushes.
// bmax triangle + Mspan are block-local LDS. E / elT are read-only cached.
// Quadrants: w==1: TT (ch0-7); w>=2: TN(ch0-3) NT(ch4-7) NN(ch8-9, w>=3).

#define NMAX 28

// LDS float offsets
#define O_ELT 0        // 64*29 (restaged each width; clobbered by red)
#define O_BW1 1856     // 32*30 (eB row w-1, built in finalize)
#define O_ELN 2816     // 5888: NN left rows [kk-1][sym][s] pitch SP
#define O_ERN 8704     // 5888: NN right rows shifted
#define O_BMX 14592    // 28*28 bmax triangle [lvl][pos] (PERSISTENT)
#define O_G   15376    // 28*28 g[k][s]
#define O_MSP 16160    // 32 Mspan (persists into next width's finalize)
#define O_NUM 16192    // 27*516 numer
#define LDSF  30124
// red[g16][s*32+a] = 16*896 = 14336 floats aliases [0,14336) (ELT..ERN dead)

__device__ __forceinline__ float gload(const float* p) {
    return __hip_atomic_load(p, __ATOMIC_RELAXED, __HIP_MEMORY_SCOPE_AGENT);
}
__device__ __forceinline__ void gstore(float* p, float v) {
    __hip_atomic_store(p, v, __ATOMIC_RELAXED, __HIP_MEMORY_SCOPE_AGENT);
}

__global__ __launch_bounds__(256) void mrule_kernel(const float* __restrict__ rule,
                                                    float* __restrict__ mrule) {
    int a = blockIdx.x, b = blockIdx.y, tid = threadIdx.x;
    const float* base = rule + (size_t)(b * 32 + a) * 9216;
    float v = -3.0e38f;
    for (int i = tid; i < 9216; i += 256) v = fmaxf(v, base[i]);
    for (int off = 32; off > 0; off >>= 1) v = fmaxf(v, __shfl_xor(v, off, 64));
    __shared__ float red[4];
    if ((tid & 63) == 0) red[tid >> 6] = v;
    __syncthreads();
    if (tid == 0)
        mrule[b * 32 + a] = fmaxf(fmaxf(red[0], red[1]), fmaxf(red[2], red[3]));
}

__global__ __launch_bounds__(256) void pack_kernel(const float* __restrict__ rule,
                                                   const float* __restrict__ mrule,
                                                   float* __restrict__ E_TT,
                                                   float* __restrict__ E_TN,
                                                   float* __restrict__ E_NT,
                                                   float* __restrict__ E_NN) {
    int b = blockIdx.y, tid = threadIdx.x;
    int a = tid & 31;
    int cc = blockIdx.x * 8 + (tid >> 5); // 0..2303
    float mr = mrule[b * 32 + a];
    int l, r;
    float* dst;
    if (cc < 1024) {
        int flat = cc * 4;
        l = 32 + (flat >> 6); r = 32 + (flat & 63);
        dst = E_TT + ((size_t)(b * 1024 + cc) * 32 + a) * 4;
    } else if (cc < 1536) {
        int flat = (cc - 1024) * 4;
        l = 32 + (flat >> 5); r = flat & 31;
        dst = E_TN + ((size_t)(b * 512 + (cc - 1024)) * 32 + a) * 4;
    } else if (cc < 2048) {
        int flat = (cc - 1536) * 4;
        l = flat >> 6; r = 32 + (flat & 63);
        dst = E_NT + ((size_t)(b * 512 + (cc - 1536)) * 32 + a) * 4;
    } else {
        int flat = (cc - 2048) * 4;
        l = flat >> 5; r = flat & 31;
        dst = E_NN + ((size_t)(b * 256 + (cc - 2048)) * 32 + a) * 4;
    }
    const float4 v = *(const float4*)(rule + (((size_t)(b * 32 + a) * 96 + l) * 96 + r));
    float4 o;
    o.x = expf(v.x - mr); o.y = expf(v.y - mr);
    o.z = expf(v.z - mr); o.w = expf(v.w - mr);
    *(float4*)dst = o;
}

__global__ __launch_bounds__(256) void prep_kernel(const float* __restrict__ unary,
                                                   const float* __restrict__ mrule,
                                                   float* __restrict__ elT_g,
                                                   float* __restrict__ bmax0_g,
                                                   float* __restrict__ emrule,
                                                   unsigned* __restrict__ cnt, int n) {
    int b = blockIdx.x, tid = threadIdx.x;
    if (tid == 0) cnt[b] = 0u;
    if (tid < 32) emrule[b * 32 + tid] = expf(mrule[b * 32 + tid]);
    for (int pos = tid >> 6; pos < n; pos += 4) {
        int t = tid & 63;
        float v = unary[((size_t)(b * n) + pos) * 64 + t];
        float m = v;
        for (int off = 32; off > 0; off >>= 1) m = fmaxf(m, __shfl_xor(m, off, 64));
        elT_g[((size_t)(b * n) + pos) * 64 + t] = expf(v - m);
        if (t == 0) bmax0_g[b * n + pos] = m;
    }
}

__global__ __launch_bounds__(512, 1) void inside_kernel(
    const float* __restrict__ elT_g, const float* __restrict__ emrule,
    const float* __restrict__ bmax0_g, float* __restrict__ eB_g,
    const float* __restrict__ E_TT, const float* __restrict__ E_TN,
    const float* __restrict__ E_NT, const float* __restrict__ E_NN,
    float* __restrict__ partA, float* __restrict__ partB,
    const float* __restrict__ mrule, const float* __restrict__ root,
    float* __restrict__ out, unsigned* __restrict__ cnt, int n) {
    extern __shared__ float lds[];
    const int b = blockIdx.x / 10, ch = blockIdx.x % 10;
    const int tid = threadIdx.x;
    const int a = tid & 31, g16 = tid >> 5;

    // ---- E register load: initial role (TT for ch<8, NN for ch>=8) ----
    float4 e4[8];
    {
        const float4* Eq = (ch < 8)
            ? (const float4*)E_TT + (size_t)b * 32768 + (size_t)(ch * 128) * 32
            : (const float4*)E_NN + (size_t)b * 8192 + (size_t)((ch - 8) * 128) * 32;
        #pragma unroll
        for (int i = 0; i < 8; ++i) e4[i] = Eq[(size_t)(g16 * 8 + i) * 32 + a];
    }

    for (int w = 1; w < n; ++w) {
        const int S = n - w, SP = S | 1;

        // ---- barrier: wait for width w-1 complete (per-batch, monotone) ----
        if (w >= 2) {
            if (tid == 0) {
                const unsigned tgt = 10u * (unsigned)(w - 1);
                while (__hip_atomic_load(&cnt[b], __ATOMIC_RELAXED,
                                         __HIP_MEMORY_SCOPE_AGENT) < tgt)
                    __builtin_amdgcn_s_sleep(4);
            }
            __syncthreads();
        }

        const bool active = (w == 1) ? (ch < 8) : (ch < 8 || w >= 3);
        int quad, cc0;
        if (w == 1)      { quad = 0; cc0 = ch * 512; }
        else if (ch < 4) { quad = 1; cc0 = ch * 512; }
        else if (ch < 8) { quad = 2; cc0 = (ch - 4) * 512; }
        else             { quad = 3; cc0 = (ch - 8) * 512; }

        // ---- phase A: restage elT; finalize prev width; NN staging ----
        for (int idx = tid; idx < n * 64; idx += 512) {
            int pos = idx >> 6, t = idx & 63;
            lds[O_ELT + t * 29 + pos] = elT_g[((size_t)b * n + pos) * 64 + t];
        }
        if (w == 1) {
            if (tid < n) lds[O_BMX + tid] = bmax0_g[b * n + tid];
        } else {
            const int wp = w - 1, Sp = S + 1;
            const int CHp = (wp >= 3) ? 10 : 8;
            const float* pb = ((w & 1) ? partA : partB) + (size_t)b * 8640;
            for (int e = tid; e < Sp * 32; e += 512) {
                float t = 0.f;
                for (int c = 0; c < CHp; ++c) t += gload(&pb[c * 864 + e]);
                int s = e >> 5, aa = e & 31;
                float t2 = t * emrule[b * 32 + aa];
                float m2 = t2;
                for (int off = 16; off > 0; off >>= 1)
                    m2 = fmaxf(m2, __shfl_xor(m2, off, 32));
                float eB = t2 / m2;
                lds[O_BW1 + aa * 30 + s] = eB;
                if (ch == 0)
                    gstore(&eB_g[(((size_t)b * n + wp) * n + s) * 32 + aa], eB);
                if (aa == 0)
                    lds[O_BMX + wp * NMAX + s] = logf(m2) + lds[O_MSP + s];
            }
            if (ch >= 8 && w >= 3) {
                for (int kk = 1; kk <= w - 2; ++kk) {
                    const float* rowL = eB_g + (((size_t)b * n + kk) * n) * 32;
                    const float* rowR = eB_g + (((size_t)b * n + (w - 1 - kk)) * n) * 32;
                    for (int idx = tid; idx < S * 32; idx += 512) {
                        int s = idx >> 5, sym = idx & 31;
                        lds[O_ELN + (kk - 1) * 32 * SP + sym * SP + s] =
                            gload(&rowL[s * 32 + sym]);
                        lds[O_ERN + (kk - 1) * 32 * SP + sym * SP + s] =
                            gload(&rowR[(s + kk + 1) * 32 + sym]);
                    }
                }
            }
        }
        __syncthreads();

        // ---- phase B: Mspan + g[k][s] (block-local) ----
        if (tid < S) {
            int s = tid;
            float M = -3.0e38f;
            for (int k = 0; k < w; ++k)
                M = fmaxf(M, lds[O_BMX + k * NMAX + s] +
                              lds[O_BMX + (w - 1 - k) * NMAX + s + k + 1]);
            lds[O_MSP + s] = M;
            for (int k = 0; k < w; ++k)
                lds[O_G + k * NMAX + s] =
                    expf(lds[O_BMX + k * NMAX + s] +
                         lds[O_BMX + (w - 1 - k) * NMAX + s + k + 1] - M);
        }
        __syncthreads();

        // ---- phase C: numer build ----
        if (active) {
            const int cc = cc0 + tid;
            int l, r;
            if (quad == 0 || quad == 2) { l = cc >> 6; r = cc & 63; }
            else                        { l = cc >> 5; r = cc & 31; }
            for (int s = 0; s < S; ++s) {
                float v;
                if (quad == 0)
                    v = lds[O_ELT + l * 29 + s] * lds[O_ELT + r * 29 + (s + 1)] *
                        lds[O_G + s];
                else if (quad == 1)
                    v = lds[O_ELT + l * 29 + s] * lds[O_BW1 + r * 30 + (s + 1)] *
                        lds[O_G + s];
                else if (quad == 2)
                    v = lds[O_BW1 + l * 30 + s] * lds[O_ELT + r * 29 + (s + w)] *
                        lds[O_G + (w - 1) * NMAX + s];
                else {
                    float acc = 0.f;
                    for (int k = 1; k <= w - 2; ++k)
                        acc = fmaf(lds[O_ELN + (k - 1) * 32 * SP + l * SP + s],
                                   lds[O_ERN + (k - 1) * 32 * SP + r * SP + s] *
                                       lds[O_G + k * NMAX + s],
                                   acc);
                    v = acc;
                }
                lds[O_NUM + s * 516 + tid] = v;
            }
        }
        __syncthreads();

        // ---- phase D: contraction (E regs x numer broadcast) -> red ----
        if (active) {
            for (int s = 0; s < S; ++s) {
                float acc = 0.f;
                #pragma unroll
                for (int i = 0; i < 8; ++i) {
                    float4 nv = *(const float4*)&lds[O_NUM + s * 516 + g16 * 32 + i * 4];
                    float4 t = e4[i];
                    acc = fmaf(nv.x, t.x,
                          fmaf(nv.y, t.y, fmaf(nv.z, t.z, fmaf(nv.w, t.w, acc))));
                }
                lds[g16 * 896 + s * 32 + a] = acc;
            }
        }
        __syncthreads();

        // ---- phase E: reduce groups -> chunk partials (bypass stores) ----
        if (active) {
            float* pb = ((w & 1) ? partB : partA) + (size_t)b * 8640;
            for (int e = tid; e < S * 32; e += 512) {
                float t = 0.f;
                #pragma unroll
                for (int g2 = 0; g2 < 16; ++g2) t += lds[g2 * 896 + e];
                gstore(&pb[ch * 864 + e], t);
            }
        }
        __syncthreads();   // drains all waves' vmcnt -> stores globally visible

        if (tid == 0)
            __hip_atomic_fetch_add(&cnt[b], 1u, __ATOMIC_RELAXED,
                                   __HIP_MEMORY_SCOPE_AGENT);

        // switch ch<8 blocks from TT role to TN/NT role after width 1
        if (w == 1 && ch < 8) {
            const float4* Eq = (ch < 4)
                ? (const float4*)E_TN + (size_t)b * 16384 + (size_t)(ch * 128) * 32
                : (const float4*)E_NT + (size_t)b * 16384 + (size_t)((ch - 4) * 128) * 32;
            #pragma unroll
            for (int i = 0; i < 8; ++i) e4[i] = Eq[(size_t)(g16 * 8 + i) * 32 + a];
        }
    }

    // ---- epilogue (ch==0 per batch): finalize width n-1 span 0 + root ----
    if (ch == 0) {
        if (tid == 0) {
            const unsigned tgt = 10u * (unsigned)(n - 1);
            while (__hip_atomic_load(&cnt[b], __ATOMIC_RELAXED,
                                     __HIP_MEMORY_SCOPE_AGENT) < tgt)
                __builtin_amdgcn_s_sleep(4);
        }
        __syncthreads();
        if (tid < 32) {
            const float* pb = (((n - 1) & 1) ? partB : partA) + (size_t)b * 8640;
            float t = 0.f;
            for (int c = 0; c < 10; ++c) t += gload(&pb[c * 864 + tid]);
            float v = logf(t) + lds[O_MSP + 0] + mrule[b * 32 + tid] + root[b * 32 + tid];
            float m = v;
            for (int off = 16; off > 0; off >>= 1) m = fmaxf(m, __shfl_xor(m, off, 32));
            float e = expf(v - m);
            for (int off = 16; off > 0; off >>= 1) e += __shfl_xor(e, off, 32);
            if (tid == 0) out[b] = m + logf(e);
        }
    }
}

extern "C" void kernel_launch(void* const* d_in, const int* in_sizes, int n_in,
                              void* d_out, int out_size, void* d_ws, size_t ws_size,
                              hipStream_t stream) {
    const float* unary = (const float*)d_in[0]; // B,n,64
    const float* rule  = (const float*)d_in[1]; // B,32,96,96
    const float* root  = (const float*)d_in[2]; // B,32
    float* out = (float*)d_out;

    const int B = in_sizes[2] / 32;
    int n = in_sizes[0] / (B * 64);

    float* ws = (float*)d_ws;
    float* mrule  = ws;                               // B*32
    float* emrule = mrule + (size_t)B * 32;           // B*32
    float* bmax0  = emrule + (size_t)B * 32;          // B*n
    float* eB_g   = bmax0 + (size_t)B * n;            // B*n*n*32
    float* elT_g  = eB_g + (size_t)B * n * n * 32;    // B*n*64
    float* E_TT   = elT_g + (size_t)B * n * 64;       // B*1024*32*4
    float* E_TN   = E_TT + (size_t)B * 131072;        // B*512*32*4
    float* E_NT   = E_TN + (size_t)B * 65536;         // B*512*32*4
    float* E_NN   = E_NT + (size_t)B * 65536;         // B*256*32*4
    float* partA  = E_NN + (size_t)B * 32768;         // B*8640
    float* partB  = partA + (size_t)B * 8640;
    unsigned* cnt = (unsigned*)(partB + (size_t)B * 8640); // B

    mrule_kernel<<<dim3(32, B), 256, 0, stream>>>(rule, mrule);
    pack_kernel<<<dim3(288, B), 256, 0, stream>>>(rule, mrule, E_TT, E_TN, E_NT, E_NN);
    prep_kernel<<<dim3(B), 256, 0, stream>>>(unary, mrule, elT_g, bmax0, emrule, cnt, n);

    hipFuncSetAttribute((const void*)inside_kernel,
                        hipFuncAttributeMaxDynamicSharedMemorySize, LDSF * 4);

    void* args[] = {
        (void*)&elT_g, (void*)&emrule, (void*)&bmax0, (void*)&eB_g,
        (void*)&E_TT, (void*)&E_TN, (void*)&E_NT, (void*)&E_NN,
        (void*)&partA, (void*)&partB, (void*)&mrule, (void*)&root,
        (void*)&out, (void*)&cnt, (void*)&n
    };
    hipLaunchCooperativeKernel((void*)inside_kernel, dim3(B * 10), dim3(512),
                               args, LDSF * 4, stream);
}

// Round 8
// 510.834 us; speedup vs baseline: 1.3085x; 1.3085x over previous
//
#include <hip/hip_runtime.h>
#include <cstdint>
#include <cstddef>

// PCFG inside algorithm. B=8, n=28, NT=32, T=64, ST=96.
// Multi-launch CKY steps (proven best structure). DP state exp-normalized:
// eB_g = exp(beta - bmax), bmax_g. Step kernel: grid (CH,B), 512 threads,
// block (b,ch) owns 256 pair-columns of packed erule in REGS (4 float4/thr).
// Per step: A[finalize prev + stage elT/bmax] B[Mspan + gtab] B2[k-packed
// NN tables, g folded into erK] C[numer -> bf16 LDS] D[contract: 2 b128
// bf16 reads + shift-unpack fma] E[chunk partials]. Partials/M ping-pong.
// Quadrants: w==1 TT(16ch); w>=2 TN(ch0-7) NT(ch8-15) NN(ch16-19, w>=3).

#define NMAX 28

// LDS float offsets
#define O_ELT 0        // 64*29 elT[t][pos]
#define O_BW1 1856     // 32*30 eB row w-1 [sym][s]
#define O_ELK 2816     // 8320  elK[(l*Sp2+s)*K4 + slot]
#define O_ERK 11136    // 8320  erK[(r*Sp2+s)*K4 + slot] (pre-scaled by gtab)
#define O_BMX 19456    // 28*28 bmax rows [lvl][pos]
#define O_G   20240    // 28*28 gtab[k][s]
#define O_MSP 21024    // 32
#define O_NUM 21056    // ushort area: 27 spans * 264 ushorts (pitch 528B)
#define LDSF  24620
// red[g16][s*32+a] = 16*896 floats aliases [0,14336) (ELT/BW1/ELK dead in D)

__device__ __forceinline__ float dot4acc(float4 m, float4 t, float acc) {
    return fmaf(m.x, t.x, fmaf(m.y, t.y, fmaf(m.z, t.z, fmaf(m.w, t.w, acc))));
}

__global__ __launch_bounds__(256) void mrule_kernel(const float* __restrict__ rule,
                                                    float* __restrict__ mrule) {
    int a = blockIdx.x, b = blockIdx.y, tid = threadIdx.x;
    const float* base = rule + (size_t)(b * 32 + a) * 9216;
    float v = -3.0e38f;
    for (int i = tid; i < 9216; i += 256) v = fmaxf(v, base[i]);
    for (int off = 32; off > 0; off >>= 1) v = fmaxf(v, __shfl_xor(v, off, 64));
    __shared__ float red[4];
    if ((tid & 63) == 0) red[tid >> 6] = v;
    __syncthreads();
    if (tid == 0)
        mrule[b * 32 + a] = fmaxf(fmaxf(red[0], red[1]), fmaxf(red[2], red[3]));
}

__global__ __launch_bounds__(256) void pack_kernel(const float* __restrict__ rule,
                                                   const float* __restrict__ mrule,
                                                   float* __restrict__ E_TT,
                                                   float* __restrict__ E_TN,
                                                   float* __restrict__ E_NT,
                                                   float* __restrict__ E_NN) {
    int b = blockIdx.y, tid = threadIdx.x;
    int a = tid & 31;
    int cc = blockIdx.x * 8 + (tid >> 5); // 0..2303
    float mr = mrule[b * 32 + a];
    int l, r;
    float* dst;
    if (cc < 1024) {
        int flat = cc * 4;
        l = 32 + (flat >> 6); r = 32 + (flat & 63);
        dst = E_TT + ((size_t)(b * 1024 + cc) * 32 + a) * 4;
    } else if (cc < 1536) {
        int flat = (cc - 1024) * 4;
        l = 32 + (flat >> 5); r = flat & 31;
        dst = E_TN + ((size_t)(b * 512 + (cc - 1024)) * 32 + a) * 4;
    } else if (cc < 2048) {
        int flat = (cc - 1536) * 4;
        l = flat >> 6; r = 32 + (flat & 63);
        dst = E_NT + ((size_t)(b * 512 + (cc - 1536)) * 32 + a) * 4;
    } else {
        int flat = (cc - 2048) * 4;
        l = flat >> 5; r = flat & 31;
        dst = E_NN + ((size_t)(b * 256 + (cc - 2048)) * 32 + a) * 4;
    }
    const float4 v = *(const float4*)(rule + (((size_t)(b * 32 + a) * 96 + l) * 96 + r));
    float4 o;
    o.x = expf(v.x - mr); o.y = expf(v.y - mr);
    o.z = expf(v.z - mr); o.w = expf(v.w - mr);
    *(float4*)dst = o;
}

__global__ __launch_bounds__(256) void prep_kernel(const float* __restrict__ unary,
                                                   const float* __restrict__ mrule,
                                                   float* __restrict__ elT_g,
                                                   float* __restrict__ bmax_g,
                                                   float* __restrict__ emrule, int n) {
    int b = blockIdx.x, tid = threadIdx.x;
    if (tid < 32) emrule[b * 32 + tid] = expf(mrule[b * 32 + tid]);
    for (int pos = tid >> 6; pos < n; pos += 4) {
        int t = tid & 63;
        float v = unary[((size_t)(b * n) + pos) * 64 + t];
        float m = v;
        for (int off = 32; off > 0; off >>= 1) m = fmaxf(m, __shfl_xor(m, off, 64));
        elT_g[((size_t)(b * n) + pos) * 64 + t] = expf(v - m);
        if (t == 0) bmax_g[((size_t)b * n + 0) * n + pos] = m;
    }
}

__global__ __launch_bounds__(512) void step_kernel(
    const float* __restrict__ elT_g, const float* __restrict__ emrule,
    float* __restrict__ bmax_g, float* __restrict__ eB_g,
    const float* __restrict__ E_TT, const float* __restrict__ E_TN,
    const float* __restrict__ E_NT, const float* __restrict__ E_NN,
    const float* __restrict__ pin, float* __restrict__ pout,
    const float* __restrict__ Min, float* __restrict__ Mout,
    int w, int n) {
    extern __shared__ float lds[];
    const int b = blockIdx.y, ch = blockIdx.x, tid = threadIdx.x;
    const int S = n - w, Sp2 = S | 1;
    int q4 = (w - 2 + 3) >> 2; if (!(q4 & 1)) ++q4;
    const int K4 = 4 * q4;                  // k-slot pitch (w>=3)
    const int a = tid & 31, g16 = tid >> 5;

    // ---- quadrant select + E register loads ----
    int quad, base4;
    const float4* Eq;
    if (w == 1)       { quad = 0; base4 = ch * 64;        Eq = (const float4*)E_TT + (size_t)b * 32768; }
    else if (ch < 8)  { quad = 1; base4 = ch * 64;        Eq = (const float4*)E_TN + (size_t)b * 16384; }
    else if (ch < 16) { quad = 2; base4 = (ch - 8) * 64;  Eq = (const float4*)E_NT + (size_t)b * 16384; }
    else              { quad = 3; base4 = (ch - 16) * 64; Eq = (const float4*)E_NN + (size_t)b * 8192;  }
    float4 e4[4];
    #pragma unroll
    for (int i = 0; i < 4; ++i)
        e4[i] = Eq[(size_t)(base4 + g16 * 4 + i) * 32 + a];

    // ---- phase A: stage elT + bmax rows; finalize prev width ----
    for (int idx = tid; idx < n * 64; idx += 512) {
        int pos = idx >> 6, t = idx & 63;
        lds[O_ELT + t * 29 + pos] = elT_g[((size_t)b * n + pos) * 64 + t];
    }
    {
        int hi = (w == 1) ? 1 : (w - 1);
        for (int idx = tid; idx < hi * n; idx += 512) {
            int k = idx / n, pos = idx - k * n;
            lds[O_BMX + k * NMAX + pos] = bmax_g[((size_t)b * n + k) * n + pos];
        }
    }
    if (w >= 2) {
        const int wp = w - 1, Sp = S + 1;
        const int CHp = (wp >= 3) ? 20 : 16;
        const float* pb = pin + (size_t)b * (20 * 864);
        for (int e = tid; e < Sp * 32; e += 512) {
            float t = 0.f;
            for (int c = 0; c < CHp; ++c) t += pb[c * 864 + e];
            int s = e >> 5, aa = e & 31;
            float t2 = t * emrule[b * 32 + aa];
            float m2 = t2;
            for (int off = 16; off > 0; off >>= 1)
                m2 = fmaxf(m2, __shfl_xor(m2, off, 32));
            float eB = t2 / m2;
            eB_g[(((size_t)b * n + wp) * n + s) * 32 + aa] = eB;
            lds[O_BW1 + aa * 30 + s] = eB;
            if (aa == 0) {
                float bm = logf(m2) + Min[b * NMAX + s];
                lds[O_BMX + wp * NMAX + s] = bm;
                bmax_g[((size_t)b * n + wp) * n + s] = bm;
            }
        }
    }
    __syncthreads();

    // ---- phase B: Mspan + gtab[k][s] (redundant M per (k,s) thread) ----
    for (int idx = tid; idx < w * 32; idx += 512) {
        int k = idx >> 5, s = idx & 31;
        if (s < S) {
            float M = -3.0e38f;
            for (int k2 = 0; k2 < w; ++k2)
                M = fmaxf(M, lds[O_BMX + k2 * NMAX + s] +
                              lds[O_BMX + (w - 1 - k2) * NMAX + s + k2 + 1]);
            lds[O_G + k * NMAX + s] =
                expf(lds[O_BMX + k * NMAX + s] +
                     lds[O_BMX + (w - 1 - k) * NMAX + s + k + 1] - M);
            if (k == 0) lds[O_MSP + s] = M;
        }
    }
    __syncthreads();

    // ---- phase B2 (w>=3): k-packed NN tables, g folded into erK ----
    if (w >= 3) {
        for (int idx = tid; idx < S * 32; idx += 512) {
            int s = idx >> 5, sym = idx & 31;
            int off = (sym * Sp2 + s) * K4;
            for (int kk = 1; kk <= w - 2; ++kk) {
                lds[O_ELK + off + kk - 1] =
                    eB_g[(((size_t)b * n + kk) * n + s) * 32 + sym];
                lds[O_ERK + off + kk - 1] =
                    eB_g[(((size_t)b * n + (w - 1 - kk)) * n + (s + kk + 1)) * 32 + sym] *
                    lds[O_G + kk * NMAX + s];
            }
            for (int k = w - 2; k < K4; ++k) {
                lds[O_ELK + off + k] = 0.f;
                lds[O_ERK + off + k] = 0.f;
            }
        }
        __syncthreads();
    }

    // ---- phase C: numer build -> bf16 LDS ----
    {
        const int cL = tid & 255, sh = tid >> 8;
        int l, r;
        if (quad == 0)      { int cc = ch * 256 + cL;        l = cc >> 6; r = cc & 63; }
        else if (quad == 1) { int cc = ch * 256 + cL;        l = cc >> 5; r = cc & 31; }
        else if (quad == 2) { int cc = (ch - 8) * 256 + cL;  l = cc >> 6; r = cc & 63; }
        else                { int cc = (ch - 16) * 256 + cL; l = cc >> 5; r = cc & 31; }
        unsigned short* np = (unsigned short*)(lds + O_NUM);
        for (int s = sh; s < S; s += 2) {
            float v;
            if (quad == 0)
                v = lds[O_ELT + l * 29 + s] * lds[O_ELT + r * 29 + (s + 1)] *
                    lds[O_G + s];
            else if (quad == 1)
                v = lds[O_ELT + l * 29 + s] * lds[O_BW1 + r * 30 + (s + 1)] *
                    lds[O_G + s];
            else if (quad == 2)
                v = lds[O_BW1 + l * 30 + s] * lds[O_ELT + r * 29 + (s + w)] *
                    lds[O_G + (w - 1) * NMAX + s];
            else {
                const float* elp = lds + O_ELK + (l * Sp2 + s) * K4;
                const float* erp = lds + O_ERK + (r * Sp2 + s) * K4;
                float acc = 0.f;
                for (int j = 0; j < K4; j += 4)
                    acc = dot4acc(*(const float4*)(elp + j),
                                  *(const float4*)(erp + j), acc);
                v = acc;
            }
            unsigned u = __float_as_uint(v);
            np[s * 264 + cL] = (unsigned short)((u + 0x7fffu + ((u >> 16) & 1u)) >> 16);
        }
    }
    __syncthreads();

    // ---- phase D: contraction (bf16 numer b128 reads, E f32 regs) ----
    {
        const char* nbase = (const char*)(lds + O_NUM);
        for (int s = 0; s < S; ++s) {
            uint4 u0 = *(const uint4*)(nbase + s * 528 + g16 * 32);
            uint4 u1 = *(const uint4*)(nbase + s * 528 + g16 * 32 + 16);
            float acc = 0.f;
            #define LO(q) __uint_as_float((q) << 16)
            #define HI(q) __uint_as_float((q) & 0xffff0000u)
            acc = fmaf(LO(u0.x), e4[0].x, acc); acc = fmaf(HI(u0.x), e4[0].y, acc);
            acc = fmaf(LO(u0.y), e4[0].z, acc); acc = fmaf(HI(u0.y), e4[0].w, acc);
            acc = fmaf(LO(u0.z), e4[1].x, acc); acc = fmaf(HI(u0.z), e4[1].y, acc);
            acc = fmaf(LO(u0.w), e4[1].z, acc); acc = fmaf(HI(u0.w), e4[1].w, acc);
            acc = fmaf(LO(u1.x), e4[2].x, acc); acc = fmaf(HI(u1.x), e4[2].y, acc);
            acc = fmaf(LO(u1.y), e4[2].z, acc); acc = fmaf(HI(u1.y), e4[2].w, acc);
            acc = fmaf(LO(u1.z), e4[3].x, acc); acc = fmaf(HI(u1.z), e4[3].y, acc);
            acc = fmaf(LO(u1.w), e4[3].z, acc); acc = fmaf(HI(u1.w), e4[3].w, acc);
            #undef LO
            #undef HI
            lds[g16 * 896 + s * 32 + a] = acc;   // red region (aliases tables)
        }
    }
    __syncthreads();

    // ---- phase E: reduce groups -> chunk partials + M ----
    {
        float* pb = pout + (size_t)b * (20 * 864);
        for (int e = tid; e < S * 32; e += 512) {
            float t = 0.f;
            #pragma unroll
            for (int g2 = 0; g2 < 16; ++g2) t += lds[g2 * 896 + e];
            pb[ch * 864 + e] = t;
        }
        if (tid < S) Mout[b * NMAX + tid] = lds[O_MSP + tid];
    }
}

// ---- final: reduce level n-1 span-0 partials, add root, logsumexp ----
__global__ void final_kernel(const float* __restrict__ pin,
                             const float* __restrict__ Min,
                             const float* __restrict__ mrule,
                             const float* __restrict__ root,
                             float* __restrict__ out, int n) {
    int b = blockIdx.x, a = threadIdx.x; // 32 threads
    int CHp = ((n - 1) >= 3) ? 20 : 16;
    const float* pb = pin + (size_t)b * (20 * 864);
    float t = 0.f;
    for (int c = 0; c < CHp; ++c) t += pb[c * 864 + a];
    float v = logf(t) + Min[b * NMAX] + mrule[b * 32 + a] + root[b * 32 + a];
    float m = v;
    for (int off = 16; off > 0; off >>= 1) m = fmaxf(m, __shfl_xor(m, off, 32));
    float e = expf(v - m);
    for (int off = 16; off > 0; off >>= 1) e += __shfl_xor(e, off, 32);
    if (a == 0) out[b] = m + logf(e);
}

extern "C" void kernel_launch(void* const* d_in, const int* in_sizes, int n_in,
                              void* d_out, int out_size, void* d_ws, size_t ws_size,
                              hipStream_t stream) {
    const float* unary = (const float*)d_in[0]; // B,n,64
    const float* rule  = (const float*)d_in[1]; // B,32,96,96
    const float* root  = (const float*)d_in[2]; // B,32
    float* out = (float*)d_out;

    const int B = in_sizes[2] / 32;
    int n = in_sizes[0] / (B * 64);

    float* ws = (float*)d_ws;
    float* mrule  = ws;                               // B*32
    float* emrule = mrule + (size_t)B * 32;           // B*32
    float* bmax_g = emrule + (size_t)B * 32;          // B*n*n
    float* eB_g   = bmax_g + (size_t)B * n * n;       // B*n*n*32
    float* elT_g  = eB_g + (size_t)B * n * n * 32;    // B*n*64
    float* E_TT   = elT_g + (size_t)B * n * 64;       // B*1024*32*4
    float* E_TN   = E_TT + (size_t)B * 131072;        // B*512*32*4
    float* E_NT   = E_TN + (size_t)B * 65536;         // B*512*32*4
    float* E_NN   = E_NT + (size_t)B * 65536;         // B*256*32*4
    float* partA  = E_NN + (size_t)B * 32768;         // B*20*864
    float* partB  = partA + (size_t)B * 20 * 864;
    float* MbufA  = partB + (size_t)B * 20 * 864;     // B*28
    float* MbufB  = MbufA + (size_t)B * NMAX;

    mrule_kernel<<<dim3(32, B), 256, 0, stream>>>(rule, mrule);
    pack_kernel<<<dim3(288, B), 256, 0, stream>>>(rule, mrule, E_TT, E_TN, E_NT, E_NN);
    prep_kernel<<<dim3(B), 256, 0, stream>>>(unary, mrule, elT_g, bmax_g, emrule, n);

    hipFuncSetAttribute((const void*)step_kernel,
                        hipFuncAttributeMaxDynamicSharedMemorySize, LDSF * 4);

    float* pbuf[2] = { partA, partB };
    float* mbuf[2] = { MbufA, MbufB };
    for (int w = 1; w < n; ++w) {
        int CH = (w >= 3) ? 20 : 16;
        step_kernel<<<dim3(CH, B), 512, LDSF * 4, stream>>>(
            elT_g, emrule, bmax_g, eB_g, E_TT, E_TN, E_NT, E_NN,
            pbuf[1 - (w & 1)], pbuf[w & 1], mbuf[1 - (w & 1)], mbuf[w & 1], w, n);
    }
    final_kernel<<<dim3(B), 32, 0, stream>>>(pbuf[(n - 1) & 1], mbuf[(n - 1) & 1],
                                             mrule, root, out, n);
}

// Round 9
// 385.598 us; speedup vs baseline: 1.7334x; 1.3248x over previous
//
#include <hip/hip_runtime.h>
#include <cstdint>
#include <cstddef>

// PCFG inside algorithm. B=8, n=28, NT=32, T=64, ST=96.
// Multi-launch CKY steps. DP state exp-normalized: eB_g = exp(beta - bmax),
// bmax_g. Step kernel: grid (20,B), 512 threads, block (b,ch) owns 256
// pair-columns of packed erule in REGS (4 float4/thr).
// Key latency fixes: finalize reads are 20 FULLY-UNROLLED independent loads
// (inactive chunks always write zero partials so the count is compile-time);
// NN table staging (B2) runs only on NN chunks with 4-wide load prefetch.
// Quadrants: w==1 TT(ch0-15); w>=2 TN(ch0-7) NT(ch8-15) NN(ch16-19, w>=3).

#define NMAX 28

// LDS float offsets
#define O_ELT 0        // 64*29 elT[t][pos]
#define O_BW1 1856     // 32*30 eB row w-1 [sym][s]
#define O_ELK 2816     // 8320  elK[(l*Sp2+s)*K4 + slot]
#define O_ERK 11136    // 8320  erK[(r*Sp2+s)*K4 + slot] (pre-scaled by gtab)
#define O_BMX 19456    // 28*28 bmax rows [lvl][pos]
#define O_G   20240    // 28*28 gtab[k][s]
#define O_MSP 21024    // 32
#define O_NUM 21056    // ushort area: 27 spans * 264 ushorts (pitch 528B)
#define LDSF  24620
// red[g16][s*32+a] = 16*896 floats aliases [0,14336) (ELT/BW1/ELK dead in D)

__device__ __forceinline__ float dot4acc(float4 m, float4 t, float acc) {
    return fmaf(m.x, t.x, fmaf(m.y, t.y, fmaf(m.z, t.z, fmaf(m.w, t.w, acc))));
}

__global__ __launch_bounds__(256) void mrule_kernel(const float* __restrict__ rule,
                                                    float* __restrict__ mrule) {
    int a = blockIdx.x, b = blockIdx.y, tid = threadIdx.x;
    const float* base = rule + (size_t)(b * 32 + a) * 9216;
    float v = -3.0e38f;
    for (int i = tid; i < 9216; i += 256) v = fmaxf(v, base[i]);
    for (int off = 32; off > 0; off >>= 1) v = fmaxf(v, __shfl_xor(v, off, 64));
    __shared__ float red[4];
    if ((tid & 63) == 0) red[tid >> 6] = v;
    __syncthreads();
    if (tid == 0)
        mrule[b * 32 + a] = fmaxf(fmaxf(red[0], red[1]), fmaxf(red[2], red[3]));
}

__global__ __launch_bounds__(256) void pack_kernel(const float* __restrict__ rule,
                                                   const float* __restrict__ mrule,
                                                   float* __restrict__ E_TT,
                                                   float* __restrict__ E_TN,
                                                   float* __restrict__ E_NT,
                                                   float* __restrict__ E_NN) {
    int b = blockIdx.y, tid = threadIdx.x;
    int a = tid & 31;
    int cc = blockIdx.x * 8 + (tid >> 5); // 0..2303
    float mr = mrule[b * 32 + a];
    int l, r;
    float* dst;
    if (cc < 1024) {
        int flat = cc * 4;
        l = 32 + (flat >> 6); r = 32 + (flat & 63);
        dst = E_TT + ((size_t)(b * 1024 + cc) * 32 + a) * 4;
    } else if (cc < 1536) {
        int flat = (cc - 1024) * 4;
        l = 32 + (flat >> 5); r = flat & 31;
        dst = E_TN + ((size_t)(b * 512 + (cc - 1024)) * 32 + a) * 4;
    } else if (cc < 2048) {
        int flat = (cc - 1536) * 4;
        l = flat >> 6; r = 32 + (flat & 63);
        dst = E_NT + ((size_t)(b * 512 + (cc - 1536)) * 32 + a) * 4;
    } else {
        int flat = (cc - 2048) * 4;
        l = flat >> 5; r = flat & 31;
        dst = E_NN + ((size_t)(b * 256 + (cc - 2048)) * 32 + a) * 4;
    }
    const float4 v = *(const float4*)(rule + (((size_t)(b * 32 + a) * 96 + l) * 96 + r));
    float4 o;
    o.x = expf(v.x - mr); o.y = expf(v.y - mr);
    o.z = expf(v.z - mr); o.w = expf(v.w - mr);
    *(float4*)dst = o;
}

__global__ __launch_bounds__(256) void prep_kernel(const float* __restrict__ unary,
                                                   const float* __restrict__ mrule,
                                                   float* __restrict__ elT_g,
                                                   float* __restrict__ bmax_g,
                                                   float* __restrict__ emrule, int n) {
    int b = blockIdx.x, tid = threadIdx.x;
    if (tid < 32) emrule[b * 32 + tid] = expf(mrule[b * 32 + tid]);
    for (int pos = tid >> 6; pos < n; pos += 4) {
        int t = tid & 63;
        float v = unary[((size_t)(b * n) + pos) * 64 + t];
        float m = v;
        for (int off = 32; off > 0; off >>= 1) m = fmaxf(m, __shfl_xor(m, off, 64));
        elT_g[((size_t)(b * n) + pos) * 64 + t] = expf(v - m);
        if (t == 0) bmax_g[((size_t)b * n + 0) * n + pos] = m;
    }
}

__global__ __launch_bounds__(512) void step_kernel(
    const float* __restrict__ elT_g, const float* __restrict__ emrule,
    float* __restrict__ bmax_g, float* __restrict__ eB_g,
    const float* __restrict__ E_TT, const float* __restrict__ E_TN,
    const float* __restrict__ E_NT, const float* __restrict__ E_NN,
    const float* __restrict__ pin, float* __restrict__ pout,
    const float* __restrict__ Min, float* __restrict__ Mout,
    int w, int n) {
    extern __shared__ float lds[];
    const int b = blockIdx.y, ch = blockIdx.x, tid = threadIdx.x;
    const int S = n - w, Sp2 = S | 1;
    int q4 = (w - 2 + 3) >> 2; if (!(q4 & 1)) ++q4;
    const int K4 = 4 * q4;                  // k-slot pitch (w>=3)
    const int a = tid & 31, g16 = tid >> 5;

    const bool active = (w == 1) ? (ch < 16) : (ch < 16 || w >= 3);

    // ---- quadrant select + E register loads ----
    int quad, base4;
    const float4* Eq;
    if (w == 1)       { quad = 0; base4 = (ch & 15) * 64; Eq = (const float4*)E_TT + (size_t)b * 32768; }
    else if (ch < 8)  { quad = 1; base4 = ch * 64;        Eq = (const float4*)E_TN + (size_t)b * 16384; }
    else if (ch < 16) { quad = 2; base4 = (ch - 8) * 64;  Eq = (const float4*)E_NT + (size_t)b * 16384; }
    else              { quad = 3; base4 = (ch - 16) * 64; Eq = (const float4*)E_NN + (size_t)b * 8192;  }
    float4 e4[4];
    #pragma unroll
    for (int i = 0; i < 4; ++i)
        e4[i] = Eq[(size_t)(base4 + g16 * 4 + i) * 32 + a];

    // ---- phase A: stage elT (consumers only) + bmax rows; finalize prev ----
    if (ch < 16) {
        for (int idx = tid; idx < n * 64; idx += 512) {
            int pos = idx >> 6, t = idx & 63;
            lds[O_ELT + t * 29 + pos] = elT_g[((size_t)b * n + pos) * 64 + t];
        }
    }
    {
        int hi = (w == 1) ? 1 : (w - 1);
        for (int idx = tid; idx < hi * n; idx += 512) {
            int k = idx / n, pos = idx - k * n;
            lds[O_BMX + k * NMAX + pos] = bmax_g[((size_t)b * n + k) * n + pos];
        }
    }
    if (w >= 2) {
        const int wp = w - 1;
        const int tot = (S + 1) * 32;       // multiple of 32
        const float* pb = pin + (size_t)b * (20 * 864);
        #pragma unroll
        for (int rep = 0; rep < 2; ++rep) {
            int e = tid + rep * 512;
            bool on = e < tot;
            float q[20];
            #pragma unroll
            for (int c = 0; c < 20; ++c) q[c] = on ? pb[c * 864 + e] : 0.f;
            float t = (((q[0] + q[1]) + (q[2] + q[3])) + ((q[4] + q[5]) + (q[6] + q[7])))
                    + (((q[8] + q[9]) + (q[10] + q[11])) + ((q[12] + q[13]) + (q[14] + q[15])))
                    + ((q[16] + q[17]) + (q[18] + q[19]));
            if (on) {
                int s = e >> 5, aa = e & 31;
                float t2 = t * emrule[b * 32 + aa];
                float m2 = t2;
                for (int off = 16; off > 0; off >>= 1)
                    m2 = fmaxf(m2, __shfl_xor(m2, off, 32));
                float eB = t2 / m2;
                lds[O_BW1 + aa * 30 + s] = eB;
                if (ch == 0)
                    eB_g[(((size_t)b * n + wp) * n + s) * 32 + aa] = eB;
                if (aa == 0) {
                    float bm = logf(m2) + Min[b * NMAX + s];
                    lds[O_BMX + wp * NMAX + s] = bm;
                    if (ch == 0) bmax_g[((size_t)b * n + wp) * n + s] = bm;
                }
            }
        }
    }
    __syncthreads();

    // ---- phase B: Mspan + gtab[k][s] ----
    for (int idx = tid; idx < w * 32; idx += 512) {
        int k = idx >> 5, s = idx & 31;
        if (s < S) {
            float M = -3.0e38f;
            for (int k2 = 0; k2 < w; ++k2)
                M = fmaxf(M, lds[O_BMX + k2 * NMAX + s] +
                              lds[O_BMX + (w - 1 - k2) * NMAX + s + k2 + 1]);
            lds[O_G + k * NMAX + s] =
                expf(lds[O_BMX + k * NMAX + s] +
                     lds[O_BMX + (w - 1 - k) * NMAX + s + k + 1] - M);
            if (k == 0) lds[O_MSP + s] = M;
        }
    }
    __syncthreads();

    // ---- phase B2 (NN chunks only): k-packed tables, g folded into erK ----
    if (w >= 3 && ch >= 16) {
        const int m = w - 2;
        for (int idx = tid; idx < S * 32; idx += 512) {
            int s = idx >> 5, sym = idx & 31;
            int off = (sym * Sp2 + s) * K4;
            for (int kk = 1; kk <= m; kk += 4) {
                float l0, l1, l2, l3, r0, r1, r2, r3;
                l0 = eB_g[(((size_t)b * n + kk) * n + s) * 32 + sym];
                r0 = eB_g[(((size_t)b * n + (w - 1 - kk)) * n + (s + kk + 1)) * 32 + sym];
                if (kk + 1 <= m) {
                    l1 = eB_g[(((size_t)b * n + kk + 1) * n + s) * 32 + sym];
                    r1 = eB_g[(((size_t)b * n + (w - 2 - kk)) * n + (s + kk + 2)) * 32 + sym];
                }
                if (kk + 2 <= m) {
                    l2 = eB_g[(((size_t)b * n + kk + 2) * n + s) * 32 + sym];
                    r2 = eB_g[(((size_t)b * n + (w - 3 - kk)) * n + (s + kk + 3)) * 32 + sym];
                }
                if (kk + 3 <= m) {
                    l3 = eB_g[(((size_t)b * n + kk + 3) * n + s) * 32 + sym];
                    r3 = eB_g[(((size_t)b * n + (w - 4 - kk)) * n + (s + kk + 4)) * 32 + sym];
                }
                lds[O_ELK + off + kk - 1] = l0;
                lds[O_ERK + off + kk - 1] = r0 * lds[O_G + kk * NMAX + s];
                if (kk + 1 <= m) {
                    lds[O_ELK + off + kk] = l1;
                    lds[O_ERK + off + kk] = r1 * lds[O_G + (kk + 1) * NMAX + s];
                }
                if (kk + 2 <= m) {
                    lds[O_ELK + off + kk + 1] = l2;
                    lds[O_ERK + off + kk + 1] = r2 * lds[O_G + (kk + 2) * NMAX + s];
                }
                if (kk + 3 <= m) {
                    lds[O_ELK + off + kk + 2] = l3;
                    lds[O_ERK + off + kk + 2] = r3 * lds[O_G + (kk + 3) * NMAX + s];
                }
            }
            for (int k = m; k < K4; ++k) {
                lds[O_ELK + off + k] = 0.f;
                lds[O_ERK + off + k] = 0.f;
            }
        }
        __syncthreads();   // block-uniform (ch is uniform per block)
    }

    // ---- phase C: numer build -> bf16 LDS ----
    if (active) {
        const int cL = tid & 255, sh = tid >> 8;
        int l, r;
        if (quad == 0)      { int cc = ch * 256 + cL;        l = cc >> 6; r = cc & 63; }
        else if (quad == 1) { int cc = ch * 256 + cL;        l = cc >> 5; r = cc & 31; }
        else if (quad == 2) { int cc = (ch - 8) * 256 + cL;  l = cc >> 6; r = cc & 63; }
        else                { int cc = (ch - 16) * 256 + cL; l = cc >> 5; r = cc & 31; }
        unsigned short* np = (unsigned short*)(lds + O_NUM);
        for (int s = sh; s < S; s += 2) {
            float v;
            if (quad == 0)
                v = lds[O_ELT + l * 29 + s] * lds[O_ELT + r * 29 + (s + 1)] *
                    lds[O_G + s];
            else if (quad == 1)
                v = lds[O_ELT + l * 29 + s] * lds[O_BW1 + r * 30 + (s + 1)] *
                    lds[O_G + s];
            else if (quad == 2)
                v = lds[O_BW1 + l * 30 + s] * lds[O_ELT + r * 29 + (s + w)] *
                    lds[O_G + (w - 1) * NMAX + s];
            else {
                const float* elp = lds + O_ELK + (l * Sp2 + s) * K4;
                const float* erp = lds + O_ERK + (r * Sp2 + s) * K4;
                float acc = 0.f;
                for (int j = 0; j < K4; j += 4)
                    acc = dot4acc(*(const float4*)(elp + j),
                                  *(const float4*)(erp + j), acc);
                v = acc;
            }
            unsigned u = __float_as_uint(v);
            np[s * 264 + cL] = (unsigned short)((u + 0x7fffu + ((u >> 16) & 1u)) >> 16);
        }
    }
    __syncthreads();

    // ---- phase D: contraction (bf16 numer b128 reads, E f32 regs) ----
    if (active) {
        const char* nbase = (const char*)(lds + O_NUM);
        for (int s = 0; s < S; ++s) {
            uint4 u0 = *(const uint4*)(nbase + s * 528 + g16 * 32);
            uint4 u1 = *(const uint4*)(nbase + s * 528 + g16 * 32 + 16);
            float acc = 0.f;
            #define LO(q) __uint_as_float((q) << 16)
            #define HI(q) __uint_as_float((q) & 0xffff0000u)
            acc = fmaf(LO(u0.x), e4[0].x, acc); acc = fmaf(HI(u0.x), e4[0].y, acc);
            acc = fmaf(LO(u0.y), e4[0].z, acc); acc = fmaf(HI(u0.y), e4[0].w, acc);
            acc = fmaf(LO(u0.z), e4[1].x, acc); acc = fmaf(HI(u0.z), e4[1].y, acc);
            acc = fmaf(LO(u0.w), e4[1].z, acc); acc = fmaf(HI(u0.w), e4[1].w, acc);
            acc = fmaf(LO(u1.x), e4[2].x, acc); acc = fmaf(HI(u1.x), e4[2].y, acc);
            acc = fmaf(LO(u1.y), e4[2].z, acc); acc = fmaf(HI(u1.y), e4[2].w, acc);
            acc = fmaf(LO(u1.z), e4[3].x, acc); acc = fmaf(HI(u1.z), e4[3].y, acc);
            acc = fmaf(LO(u1.w), e4[3].z, acc); acc = fmaf(HI(u1.w), e4[3].w, acc);
            #undef LO
            #undef HI
            lds[g16 * 896 + s * 32 + a] = acc;   // red region (aliases tables)
        }
    }
    __syncthreads();

    // ---- phase E: reduce groups -> chunk partials + M ----
    {
        float* pb = pout + (size_t)b * (20 * 864);
        for (int e = tid; e < S * 32; e += 512) {
            float t = 0.f;
            if (active) {
                #pragma unroll
                for (int g2 = 0; g2 < 16; ++g2) t += lds[g2 * 896 + e];
            }
            pb[ch * 864 + e] = t;
        }
        if (tid < S) Mout[b * NMAX + tid] = lds[O_MSP + tid];
    }
}

// ---- final: reduce level n-1 span-0 partials, add root, logsumexp ----
__global__ void final_kernel(const float* __restrict__ pin,
                             const float* __restrict__ Min,
                             const float* __restrict__ mrule,
                             const float* __restrict__ root,
                             float* __restrict__ out, int n) {
    int b = blockIdx.x, a = threadIdx.x; // 32 threads
    const float* pb = pin + (size_t)b * (20 * 864);
    float q[20];
    #pragma unroll
    for (int c = 0; c < 20; ++c) q[c] = pb[c * 864 + a];
    float t = (((q[0] + q[1]) + (q[2] + q[3])) + ((q[4] + q[5]) + (q[6] + q[7])))
            + (((q[8] + q[9]) + (q[10] + q[11])) + ((q[12] + q[13]) + (q[14] + q[15])))
            + ((q[16] + q[17]) + (q[18] + q[19]));
    float v = logf(t) + Min[b * NMAX] + mrule[b * 32 + a] + root[b * 32 + a];
    float m = v;
    for (int off = 16; off > 0; off >>= 1) m = fmaxf(m, __shfl_xor(m, off, 32));
    float e = expf(v - m);
    for (int off = 16; off > 0; off >>= 1) e += __shfl_xor(e, off, 32);
    if (a == 0) out[b] = m + logf(e);
}

extern "C" void kernel_launch(void* const* d_in, const int* in_sizes, int n_in,
                              void* d_out, int out_size, void* d_ws, size_t ws_size,
                              hipStream_t stream) {
    const float* unary = (const float*)d_in[0]; // B,n,64
    const float* rule  = (const float*)d_in[1]; // B,32,96,96
    const float* root  = (const float*)d_in[2]; // B,32
    float* out = (float*)d_out;

    const int B = in_sizes[2] / 32;
    int n = in_sizes[0] / (B * 64);

    float* ws = (float*)d_ws;
    float* mrule  = ws;                               // B*32
    float* emrule = mrule + (size_t)B * 32;           // B*32
    float* bmax_g = emrule + (size_t)B * 32;          // B*n*n
    float* eB_g   = bmax_g + (size_t)B * n * n;       // B*n*n*32
    float* elT_g  = eB_g + (size_t)B * n * n * 32;    // B*n*64
    float* E_TT   = elT_g + (size_t)B * n * 64;       // B*1024*32*4
    float* E_TN   = E_TT + (size_t)B * 131072;        // B*512*32*4
    float* E_NT   = E_TN + (size_t)B * 65536;         // B*512*32*4
    float* E_NN   = E_NT + (size_t)B * 65536;         // B*256*32*4
    float* partA  = E_NN + (size_t)B * 32768;         // B*20*864
    float* partB  = partA + (size_t)B * 20 * 864;
    float* MbufA  = partB + (size_t)B * 20 * 864;     // B*28
    float* MbufB  = MbufA + (size_t)B * NMAX;

    mrule_kernel<<<dim3(32, B), 256, 0, stream>>>(rule, mrule);
    pack_kernel<<<dim3(288, B), 256, 0, stream>>>(rule, mrule, E_TT, E_TN, E_NT, E_NN);
    prep_kernel<<<dim3(B), 256, 0, stream>>>(unary, mrule, elT_g, bmax_g, emrule, n);

    hipFuncSetAttribute((const void*)step_kernel,
                        hipFuncAttributeMaxDynamicSharedMemorySize, LDSF * 4);

    float* pbuf[2] = { partA, partB };
    float* mbuf[2] = { MbufA, MbufB };
    for (int w = 1; w < n; ++w) {
        step_kernel<<<dim3(20, B), 512, LDSF * 4, stream>>>(
            elT_g, emrule, bmax_g, eB_g, E_TT, E_TN, E_NT, E_NN,
            pbuf[1 - (w & 1)], pbuf[w & 1], mbuf[1 - (w & 1)], mbuf[w & 1], w, n);
    }
    final_kernel<<<dim3(B), 32, 0, stream>>>(pbuf[(n - 1) & 1], mbuf[(n - 1) & 1],
                                             mrule, root, out, n);
}

// Round 10
// 374.035 us; speedup vs baseline: 1.7870x; 1.0309x over previous
//
#include <hip/hip_runtime.h>
#include <cstdint>
#include <cstddef>

// PCFG inside algorithm. B=8, n=28, NT=32, T=64, ST=96.
// Persistent cooperative kernel v2: grid = B*20 blocks, 512 threads.
// Block (b,ch) owns 256 pair-columns of packed erule in REGS (4 float4/thr).
// Per width: [A] finalize prev width from chunk partials -- 20 FULLY-UNROLLED
// uncached loads, redundant per block (bitwise identical); NN blocks append
// the finalized row to a private LDS eB triangle. [B] Mspan+gtab (LDS).
// [B2] NN: k-packed ELK/ERK from LDS triangle (LDS->LDS only). [C] numer ->
// bf16 LDS. [D] contract vs E regs. [E] uncached partial stores. Then one
// monotone agent-scope counter increment; next width spins on it.
// NO global eB/bmax/M traffic at all. Partials ping-pong (WAR-safe: all
// width-w reads precede any width-(w+1) write by the barrier).
// Quadrants: w==1 TT(ch0-15); w>=2 TN(ch0-7) NT(ch8-15) NN(ch16-19, w>=3).

#define NMAX 28

// LDS float offsets (common)
#define O_BW1 0        // 32*30: eB row w-1 [sym][s]
#define O_BMX 960      // 28*28: bmax triangle [lvl][pos] (persistent)
#define O_G   1744     // 28*28: gtab[k][s]
#define O_MSP 2528     // 32: Mspan (persists into next width's finalize)
#define O_NUM 2560     // 3564 floats: ushort numer, 27 spans * 264 (528B pitch)
#define O_RED 6144     // 14336: red[g16][s*32+a]
// ch<16 role:
#define O_ELT 20480    // 64*29: elT[t][pos] (persistent, staged in prologue)
// NN role (ch>=16): ELK/ERK alias RED region (dead by phase D)
#define O_ELK 6144     // 8320: elK[(sym*Sp2+s)*K4 + slot]
#define O_ERK 14464    // 8320: erK[...] pre-scaled by gtab
#define O_TRI 22784    // 12064: eB triangle rows 1..n-2, [off32(w)+s][sym]
#define LDSF  34848

__device__ __forceinline__ int off32(int w, int n) {
    return (w - 1) * n - (w * (w - 1)) / 2;
}
__device__ __forceinline__ float gload(const float* p) {
    return __hip_atomic_load(p, __ATOMIC_RELAXED, __HIP_MEMORY_SCOPE_AGENT);
}
__device__ __forceinline__ void gstore(float* p, float v) {
    __hip_atomic_store(p, v, __ATOMIC_RELAXED, __HIP_MEMORY_SCOPE_AGENT);
}
__device__ __forceinline__ float dot4acc(float4 m, float4 t, float acc) {
    return fmaf(m.x, t.x, fmaf(m.y, t.y, fmaf(m.z, t.z, fmaf(m.w, t.w, acc))));
}

__global__ __launch_bounds__(256) void mrule_kernel(const float* __restrict__ rule,
                                                    float* __restrict__ mrule) {
    int a = blockIdx.x, b = blockIdx.y, tid = threadIdx.x;
    const float* base = rule + (size_t)(b * 32 + a) * 9216;
    float v = -3.0e38f;
    for (int i = tid; i < 9216; i += 256) v = fmaxf(v, base[i]);
    for (int off = 32; off > 0; off >>= 1) v = fmaxf(v, __shfl_xor(v, off, 64));
    __shared__ float red[4];
    if ((tid & 63) == 0) red[tid >> 6] = v;
    __syncthreads();
    if (tid == 0)
        mrule[b * 32 + a] = fmaxf(fmaxf(red[0], red[1]), fmaxf(red[2], red[3]));
}

__global__ __launch_bounds__(256) void pack_kernel(const float* __restrict__ rule,
                                                   const float* __restrict__ mrule,
                                                   float* __restrict__ E_TT,
                                                   float* __restrict__ E_TN,
                                                   float* __restrict__ E_NT,
                                                   float* __restrict__ E_NN) {
    int b = blockIdx.y, tid = threadIdx.x;
    int a = tid & 31;
    int cc = blockIdx.x * 8 + (tid >> 5); // 0..2303
    float mr = mrule[b * 32 + a];
    int l, r;
    float* dst;
    if (cc < 1024) {
        int flat = cc * 4;
        l = 32 + (flat >> 6); r = 32 + (flat & 63);
        dst = E_TT + ((size_t)(b * 1024 + cc) * 32 + a) * 4;
    } else if (cc < 1536) {
        int flat = (cc - 1024) * 4;
        l = 32 + (flat >> 5); r = flat & 31;
        dst = E_TN + ((size_t)(b * 512 + (cc - 1024)) * 32 + a) * 4;
    } else if (cc < 2048) {
        int flat = (cc - 1536) * 4;
        l = flat >> 6; r = 32 + (flat & 63);
        dst = E_NT + ((size_t)(b * 512 + (cc - 1536)) * 32 + a) * 4;
    } else {
        int flat = (cc - 2048) * 4;
        l = flat >> 5; r = flat & 31;
        dst = E_NN + ((size_t)(b * 256 + (cc - 2048)) * 32 + a) * 4;
    }
    const float4 v = *(const float4*)(rule + (((size_t)(b * 32 + a) * 96 + l) * 96 + r));
    float4 o;
    o.x = expf(v.x - mr); o.y = expf(v.y - mr);
    o.z = expf(v.z - mr); o.w = expf(v.w - mr);
    *(float4*)dst = o;
}

__global__ __launch_bounds__(256) void prep_kernel(const float* __restrict__ unary,
                                                   const float* __restrict__ mrule,
                                                   float* __restrict__ elT_g,
                                                   float* __restrict__ bmax0_g,
                                                   float* __restrict__ emrule,
                                                   unsigned* __restrict__ cnt, int n) {
    int b = blockIdx.x, tid = threadIdx.x;
    if (tid == 0) cnt[b] = 0u;
    if (tid < 32) emrule[b * 32 + tid] = expf(mrule[b * 32 + tid]);
    for (int pos = tid >> 6; pos < n; pos += 4) {
        int t = tid & 63;
        float v = unary[((size_t)(b * n) + pos) * 64 + t];
        float m = v;
        for (int off = 32; off > 0; off >>= 1) m = fmaxf(m, __shfl_xor(m, off, 64));
        elT_g[((size_t)(b * n) + pos) * 64 + t] = expf(v - m);
        if (t == 0) bmax0_g[b * n + pos] = m;
    }
}

__global__ __launch_bounds__(512, 1) void inside_kernel(
    const float* __restrict__ elT_g, const float* __restrict__ emrule,
    const float* __restrict__ bmax0_g,
    const float* __restrict__ E_TT, const float* __restrict__ E_TN,
    const float* __restrict__ E_NT, const float* __restrict__ E_NN,
    float* __restrict__ partA, float* __restrict__ partB,
    const float* __restrict__ mrule, const float* __restrict__ root,
    float* __restrict__ out, unsigned* __restrict__ cnt, int n) {
    extern __shared__ float lds[];
    const int b = blockIdx.x / 20, ch = blockIdx.x % 20;
    const int tid = threadIdx.x;
    const int a = tid & 31, g16 = tid >> 5;

    // ---- prologue: E regs (initial role), elT, bmax row 0 ----
    float4 e4[4];
    {
        const float4* Eq;
        int base4;
        if (ch < 16) { Eq = (const float4*)E_TT + (size_t)b * 32768; base4 = ch * 64; }
        else         { Eq = (const float4*)E_NN + (size_t)b * 8192;  base4 = (ch - 16) * 64; }
        #pragma unroll
        for (int i = 0; i < 4; ++i)
            e4[i] = Eq[(size_t)(base4 + g16 * 4 + i) * 32 + a];
    }
    if (ch < 16) {
        for (int idx = tid; idx < n * 64; idx += 512) {
            int pos = idx >> 6, t = idx & 63;
            lds[O_ELT + t * 29 + pos] = elT_g[((size_t)b * n + pos) * 64 + t];
        }
    }
    if (tid < n) lds[O_BMX + tid] = bmax0_g[b * n + tid];

    for (int w = 1; w < n; ++w) {
        const int S = n - w, Sp2 = S | 1;
        int q4 = (w - 2 + 3) >> 2; if (!(q4 & 1)) ++q4;
        const int K4 = 4 * q4;

        // ---- barrier: wait for width w-1 fully stored ----
        if (w >= 2) {
            if (tid == 0) {
                const unsigned tgt = 20u * (unsigned)(w - 1);
                while (__hip_atomic_load(&cnt[b], __ATOMIC_RELAXED,
                                         __HIP_MEMORY_SCOPE_AGENT) < tgt)
                    __builtin_amdgcn_s_sleep(1);
            }
        }
        __syncthreads();

        const bool active = (w == 1) ? (ch < 16) : (ch < 16 || w >= 3);
        int quad, cc0;
        if (w == 1)      { quad = 0; cc0 = ch * 256; }
        else if (ch < 8) { quad = 1; cc0 = ch * 256; }
        else if (ch < 16){ quad = 2; cc0 = (ch - 8) * 256; }
        else             { quad = 3; cc0 = (ch - 16) * 256; }

        // ---- phase A: finalize prev width (20 unrolled uncached loads) ----
        if (w >= 2) {
            const int wp = w - 1;
            const int tot = (S + 1) * 32;
            const float* pb = ((w & 1) ? partA : partB) + (size_t)b * (20 * 864);
            #pragma unroll
            for (int rep = 0; rep < 2; ++rep) {
                int e = tid + rep * 512;
                bool on = e < tot;
                float q[20];
                #pragma unroll
                for (int c = 0; c < 20; ++c) q[c] = on ? gload(&pb[c * 864 + e]) : 0.f;
                float t = (((q[0] + q[1]) + (q[2] + q[3])) + ((q[4] + q[5]) + (q[6] + q[7])))
                        + (((q[8] + q[9]) + (q[10] + q[11])) + ((q[12] + q[13]) + (q[14] + q[15])))
                        + ((q[16] + q[17]) + (q[18] + q[19]));
                if (on) {
                    int s = e >> 5, aa = e & 31;
                    float t2 = t * emrule[b * 32 + aa];
                    float m2 = t2;
                    for (int off = 16; off > 0; off >>= 1)
                        m2 = fmaxf(m2, __shfl_xor(m2, off, 32));
                    float eB = t2 / m2;
                    lds[O_BW1 + aa * 30 + s] = eB;
                    if (ch >= 16)
                        lds[O_TRI + (off32(wp, n) + s) * 32 + aa] = eB;
                    if (aa == 0)
                        lds[O_BMX + wp * NMAX + s] = logf(m2) + lds[O_MSP + s];
                }
            }
        }
        __syncthreads();

        // ---- phase B: Mspan + gtab[k][s] ----
        for (int idx = tid; idx < w * 32; idx += 512) {
            int k = idx >> 5, s = idx & 31;
            if (s < S) {
                float M = -3.0e38f;
                for (int k2 = 0; k2 < w; ++k2)
                    M = fmaxf(M, lds[O_BMX + k2 * NMAX + s] +
                                  lds[O_BMX + (w - 1 - k2) * NMAX + s + k2 + 1]);
                lds[O_G + k * NMAX + s] =
                    expf(lds[O_BMX + k * NMAX + s] +
                         lds[O_BMX + (w - 1 - k) * NMAX + s + k + 1] - M);
                if (k == 0) lds[O_MSP + s] = M;
            }
        }
        __syncthreads();

        // ---- phase B2 (NN only): k-packed tables from LDS triangle ----
        if (w >= 3 && ch >= 16) {
            const int m = w - 2;
            for (int idx = tid; idx < S * 32; idx += 512) {
                int s = idx >> 5, sym = idx & 31;
                int off = (sym * Sp2 + s) * K4;
                for (int kk = 1; kk <= m; ++kk) {
                    float l0 = lds[O_TRI + (off32(kk, n) + s) * 32 + sym];
                    float r0 = lds[O_TRI + (off32(w - 1 - kk, n) + s + kk + 1) * 32 + sym];
                    lds[O_ELK + off + kk - 1] = l0;
                    lds[O_ERK + off + kk - 1] = r0 * lds[O_G + kk * NMAX + s];
                }
                for (int k = m; k < K4; ++k) {
                    lds[O_ELK + off + k] = 0.f;
                    lds[O_ERK + off + k] = 0.f;
                }
            }
            __syncthreads();   // block-uniform (ch uniform per block)
        }

        // ---- phase C: numer build -> bf16 LDS ----
        if (active) {
            const int cL = tid & 255, sh = tid >> 8;
            const int cc = cc0 + cL;
            int l, r;
            if (quad == 0 || quad == 2) { l = cc >> 6; r = cc & 63; }
            else                        { l = cc >> 5; r = cc & 31; }
            unsigned short* np = (unsigned short*)(lds + O_NUM);
            for (int s = sh; s < S; s += 2) {
                float v;
                if (quad == 0)
                    v = lds[O_ELT + l * 29 + s] * lds[O_ELT + r * 29 + (s + 1)] *
                        lds[O_G + s];
                else if (quad == 1)
                    v = lds[O_ELT + l * 29 + s] * lds[O_BW1 + r * 30 + (s + 1)] *
                        lds[O_G + s];
                else if (quad == 2)
                    v = lds[O_BW1 + l * 30 + s] * lds[O_ELT + r * 29 + (s + w)] *
                        lds[O_G + (w - 1) * NMAX + s];
                else {
                    const float* elp = lds + O_ELK + (l * Sp2 + s) * K4;
                    const float* erp = lds + O_ERK + (r * Sp2 + s) * K4;
                    float acc = 0.f;
                    for (int j = 0; j < K4; j += 4)
                        acc = dot4acc(*(const float4*)(elp + j),
                                      *(const float4*)(erp + j), acc);
                    v = acc;
                }
                unsigned u = __float_as_uint(v);
                np[s * 264 + cL] = (unsigned short)((u + 0x7fffu + ((u >> 16) & 1u)) >> 16);
            }
        }
        __syncthreads();

        // ---- phase D: contraction (bf16 numer b128 reads, E f32 regs) ----
        if (active) {
            const char* nbase = (const char*)(lds + O_NUM);
            for (int s = 0; s < S; ++s) {
                uint4 u0 = *(const uint4*)(nbase + s * 528 + g16 * 32);
                uint4 u1 = *(const uint4*)(nbase + s * 528 + g16 * 32 + 16);
                float acc = 0.f;
                #define LO(q) __uint_as_float((q) << 16)
                #define HI(q) __uint_as_float((q) & 0xffff0000u)
                acc = fmaf(LO(u0.x), e4[0].x, acc); acc = fmaf(HI(u0.x), e4[0].y, acc);
                acc = fmaf(LO(u0.y), e4[0].z, acc); acc = fmaf(HI(u0.y), e4[0].w, acc);
                acc = fmaf(LO(u0.z), e4[1].x, acc); acc = fmaf(HI(u0.z), e4[1].y, acc);
                acc = fmaf(LO(u0.w), e4[1].z, acc); acc = fmaf(HI(u0.w), e4[1].w, acc);
                acc = fmaf(LO(u1.x), e4[2].x, acc); acc = fmaf(HI(u1.x), e4[2].y, acc);
                acc = fmaf(LO(u1.y), e4[2].z, acc); acc = fmaf(HI(u1.y), e4[2].w, acc);
                acc = fmaf(LO(u1.z), e4[3].x, acc); acc = fmaf(HI(u1.z), e4[3].y, acc);
                acc = fmaf(LO(u1.w), e4[3].z, acc); acc = fmaf(HI(u1.w), e4[3].w, acc);
                #undef LO
                #undef HI
                lds[O_RED + g16 * 896 + s * 32 + a] = acc;
            }
        }
        __syncthreads();

        // ---- phase E: reduce groups -> uncached chunk partials ----
        {
            float* pb = ((w & 1) ? partB : partA) + (size_t)b * (20 * 864);
            for (int e = tid; e < S * 32; e += 512) {
                float t = 0.f;
                if (active) {
                    #pragma unroll
                    for (int g2 = 0; g2 < 16; ++g2)
                        t += lds[O_RED + g2 * 896 + e];
                }
                gstore(&pb[ch * 864 + e], t);
            }
        }
        __syncthreads();   // drains vmcnt -> partial stores globally visible

        if (tid == 0)
            __hip_atomic_fetch_add(&cnt[b], 1u, __ATOMIC_RELAXED,
                                   __HIP_MEMORY_SCOPE_AGENT);

        // switch ch<16 blocks from TT role to TN/NT role after width 1
        if (w == 1 && ch < 16) {
            const float4* Eq = (ch < 8)
                ? (const float4*)E_TN + (size_t)b * 16384 + (size_t)(ch * 64) * 32
                : (const float4*)E_NT + (size_t)b * 16384 + (size_t)((ch - 8) * 64) * 32;
            #pragma unroll
            for (int i = 0; i < 4; ++i) e4[i] = Eq[(size_t)(g16 * 4 + i) * 32 + a];
        }
    }

    // ---- epilogue (ch==0): finalize width n-1 span 0 + root logsumexp ----
    if (ch == 0) {
        if (tid == 0) {
            const unsigned tgt = 20u * (unsigned)(n - 1);
            while (__hip_atomic_load(&cnt[b], __ATOMIC_RELAXED,
                                     __HIP_MEMORY_SCOPE_AGENT) < tgt)
                __builtin_amdgcn_s_sleep(1);
        }
        __syncthreads();
        if (tid < 32) {
            const float* pb = (((n - 1) & 1) ? partB : partA) + (size_t)b * (20 * 864);
            float q[20];
            #pragma unroll
            for (int c = 0; c < 20; ++c) q[c] = gload(&pb[c * 864 + tid]);
            float t = (((q[0] + q[1]) + (q[2] + q[3])) + ((q[4] + q[5]) + (q[6] + q[7])))
                    + (((q[8] + q[9]) + (q[10] + q[11])) + ((q[12] + q[13]) + (q[14] + q[15])))
                    + ((q[16] + q[17]) + (q[18] + q[19]));
            float v = logf(t) + lds[O_MSP + 0] + mrule[b * 32 + tid] + root[b * 32 + tid];
            float m = v;
            for (int off = 16; off > 0; off >>= 1) m = fmaxf(m, __shfl_xor(m, off, 32));
            float e = expf(v - m);
            for (int off = 16; off > 0; off >>= 1) e += __shfl_xor(e, off, 32);
            if (tid == 0) out[b] = m + logf(e);
        }
    }
}

extern "C" void kernel_launch(void* const* d_in, const int* in_sizes, int n_in,
                              void* d_out, int out_size, void* d_ws, size_t ws_size,
                              hipStream_t stream) {
    const float* unary = (const float*)d_in[0]; // B,n,64
    const float* rule  = (const float*)d_in[1]; // B,32,96,96
    const float* root  = (const float*)d_in[2]; // B,32
    float* out = (float*)d_out;

    const int B = in_sizes[2] / 32;
    int n = in_sizes[0] / (B * 64);

    float* ws = (float*)d_ws;
    float* mrule  = ws;                               // B*32
    float* emrule = mrule + (size_t)B * 32;           // B*32
    float* bmax0  = emrule + (size_t)B * 32;          // B*n
    float* elT_g  = bmax0 + (size_t)B * n;            // B*n*64
    float* E_TT   = elT_g + (size_t)B * n * 64;       // B*1024*32*4
    float* E_TN   = E_TT + (size_t)B * 131072;        // B*512*32*4
    float* E_NT   = E_TN + (size_t)B * 65536;         // B*512*32*4
    float* E_NN   = E_NT + (size_t)B * 65536;         // B*256*32*4
    float* partA  = E_NN + (size_t)B * 32768;         // B*20*864
    float* partB  = partA + (size_t)B * 20 * 864;
    unsigned* cnt = (unsigned*)(partB + (size_t)B * 20 * 864); // B

    mrule_kernel<<<dim3(32, B), 256, 0, stream>>>(rule, mrule);
    pack_kernel<<<dim3(288, B), 256, 0, stream>>>(rule, mrule, E_TT, E_TN, E_NT, E_NN);
    prep_kernel<<<dim3(B), 256, 0, stream>>>(unary, mrule, elT_g, bmax0, emrule, cnt, n);

    hipFuncSetAttribute((const void*)inside_kernel,
                        hipFuncAttributeMaxDynamicSharedMemorySize, LDSF * 4);

    void* args[] = {
        (void*)&elT_g, (void*)&emrule, (void*)&bmax0,
        (void*)&E_TT, (void*)&E_TN, (void*)&E_NT, (void*)&E_NN,
        (void*)&partA, (void*)&partB, (void*)&mrule, (void*)&root,
        (void*)&out, (void*)&cnt, (void*)&n
    };
    hipLaunchCooperativeKernel((void*)inside_kernel, dim3(B * 20), dim3(512),
                               args, LDSF * 4, stream);
}

// Round 11
// 267.920 us; speedup vs baseline: 2.4948x; 1.3961x over previous
//
#include <hip/hip_runtime.h>
#include <cstdint>
#include <cstddef>

// PCFG inside algorithm. B=8, n=28, NT=32, T=64, ST=96.
// Persistent cooperative kernel v3: grid = B*20 blocks, 1024 threads.
// Block (b,ch) owns 256 pair-columns of packed erule in REGS (2 float4/thr).
// Per width: [spin: flag-vector barrier, parallel polls] [A: finalize prev
// width from 20 fully-unrolled uncached loads (redundant per block) + NN
// blocks copy ELK from LDS triangle] [B: Mspan+gtab] [B2 NN: ERK=TRI*g]
// [C: numer -> bf16 LDS] [D: contract vs E regs, wave-pair shfl reduce]
// [E: 16-group reduce -> uncached partial stores] [publish flag].
// No global eB/bmax traffic; partials ping-pong; flags monotone.
// Quadrants: w==1 TT(ch0-15); w>=2 TN(ch0-7) NT(ch8-15) NN(ch16-19, w>=3).

#define NMAX 28

// LDS float offsets
#define O_BW1 0        // 32*30: eB row w-1 [sym][s]
#define O_BMX 960      // 28*28: bmax triangle [lvl][pos] (persistent)
#define O_G   1744     // 28*28: gtab[k][s]
#define O_MSP 2528     // 32: Mspan (persists into next width's finalize)
#define O_EMR 2560     // 32: exp(mrule)
#define O_NUM 2592     // 3564 floats: ushort numer, 27 spans * 264 (528B pitch)
#define O_RED 6160     // 14336: red[wv16][s*32+a]
// ch<16 role:
#define O_ELT 20496    // 64*29: elT[t][pos] (persistent, staged in prologue)
// NN role (ch>=16): ELK/ERK alias RED region (dead by phase D)
#define O_ELK 6160     // 8320
#define O_ERK 14480    // 8320 (upper part overlaps ELT region: ch-disjoint)
#define O_TRI 22800    // 12064: eB triangle rows 1..n-2, [off32(w)+s][sym]
#define LDSF  34864    // * 4 = 139456 B

__device__ __forceinline__ int off32(int w, int n) {
    return (w - 1) * n - (w * (w - 1)) / 2;
}
__device__ __forceinline__ float gload(const float* p) {
    return __hip_atomic_load(p, __ATOMIC_RELAXED, __HIP_MEMORY_SCOPE_AGENT);
}
__device__ __forceinline__ void gstore(float* p, float v) {
    __hip_atomic_store(p, v, __ATOMIC_RELAXED, __HIP_MEMORY_SCOPE_AGENT);
}
__device__ __forceinline__ unsigned gloadu(const unsigned* p) {
    return __hip_atomic_load(p, __ATOMIC_RELAXED, __HIP_MEMORY_SCOPE_AGENT);
}
__device__ __forceinline__ void gstoreu(unsigned* p, unsigned v) {
    __hip_atomic_store(p, v, __ATOMIC_RELAXED, __HIP_MEMORY_SCOPE_AGENT);
}
__device__ __forceinline__ float dot4acc(float4 m, float4 t, float acc) {
    return fmaf(m.x, t.x, fmaf(m.y, t.y, fmaf(m.z, t.z, fmaf(m.w, t.w, acc))));
}

__global__ __launch_bounds__(256) void mrule_kernel(const float* __restrict__ rule,
                                                    float* __restrict__ mrule,
                                                    unsigned* __restrict__ flags) {
    int a = blockIdx.x, b = blockIdx.y, tid = threadIdx.x;
    if (a == 0 && tid < 32) gstoreu(&flags[b * 32 + tid], 0u);
    const float* base = rule + (size_t)(b * 32 + a) * 9216;
    float v = -3.0e38f;
    for (int i = tid; i < 9216; i += 256) v = fmaxf(v, base[i]);
    for (int off = 32; off > 0; off >>= 1) v = fmaxf(v, __shfl_xor(v, off, 64));
    __shared__ float red[4];
    if ((tid & 63) == 0) red[tid >> 6] = v;
    __syncthreads();
    if (tid == 0)
        mrule[b * 32 + a] = fmaxf(fmaxf(red[0], red[1]), fmaxf(red[2], red[3]));
}

__global__ __launch_bounds__(256) void pack_kernel(const float* __restrict__ rule,
                                                   const float* __restrict__ mrule,
                                                   float* __restrict__ E_TT,
                                                   float* __restrict__ E_TN,
                                                   float* __restrict__ E_NT,
                                                   float* __restrict__ E_NN) {
    int b = blockIdx.y, tid = threadIdx.x;
    int a = tid & 31;
    int cc = blockIdx.x * 8 + (tid >> 5); // 0..2303
    float mr = mrule[b * 32 + a];
    int l, r;
    float* dst;
    if (cc < 1024) {
        int flat = cc * 4;
        l = 32 + (flat >> 6); r = 32 + (flat & 63);
        dst = E_TT + ((size_t)(b * 1024 + cc) * 32 + a) * 4;
    } else if (cc < 1536) {
        int flat = (cc - 1024) * 4;
        l = 32 + (flat >> 5); r = flat & 31;
        dst = E_TN + ((size_t)(b * 512 + (cc - 1024)) * 32 + a) * 4;
    } else if (cc < 2048) {
        int flat = (cc - 1536) * 4;
        l = flat >> 6; r = 32 + (flat & 63);
        dst = E_NT + ((size_t)(b * 512 + (cc - 1536)) * 32 + a) * 4;
    } else {
        int flat = (cc - 2048) * 4;
        l = flat >> 5; r = flat & 31;
        dst = E_NN + ((size_t)(b * 256 + (cc - 2048)) * 32 + a) * 4;
    }
    const float4 v = *(const float4*)(rule + (((size_t)(b * 32 + a) * 96 + l) * 96 + r));
    float4 o;
    o.x = expf(v.x - mr); o.y = expf(v.y - mr);
    o.z = expf(v.z - mr); o.w = expf(v.w - mr);
    *(float4*)dst = o;
}

__global__ __launch_bounds__(1024, 4) void inside_kernel(
    const float* __restrict__ unary, const float* __restrict__ mrule,
    const float* __restrict__ E_TT, const float* __restrict__ E_TN,
    const float* __restrict__ E_NT, const float* __restrict__ E_NN,
    float* __restrict__ partA, float* __restrict__ partB,
    const float* __restrict__ root, float* __restrict__ out,
    unsigned* __restrict__ flags, int n) {
    extern __shared__ float lds[];
    const int b = blockIdx.x / 20, ch = blockIdx.x % 20;
    const int tid = threadIdx.x;
    const int a = tid & 31;

    // ---- prologue: E regs, emrule, bmax row 0, elT ----
    float4 e4[2];
    {
        const float4* Eq;
        int base4;
        if (ch < 16) { Eq = (const float4*)E_TT + (size_t)b * 32768; base4 = ch * 64; }
        else         { Eq = (const float4*)E_NN + (size_t)b * 8192;  base4 = (ch - 16) * 64; }
        #pragma unroll
        for (int i = 0; i < 2; ++i)
            e4[i] = Eq[(size_t)(base4 + (tid >> 5) * 2 + i) * 32 + a];
    }
    if (tid < 32) lds[O_EMR + tid] = __expf(mrule[b * 32 + tid]);
    for (int pos = tid >> 6; pos < n; pos += 16) {
        int t = tid & 63;
        float v = unary[((size_t)b * n + pos) * 64 + t];
        float m = v;
        for (int off = 32; off > 0; off >>= 1) m = fmaxf(m, __shfl_xor(m, off, 64));
        if (t == 0) lds[O_BMX + pos] = m;
        if (ch < 16) lds[O_ELT + t * 29 + pos] = __expf(v - m);
    }
    __syncthreads();

    for (int w = 1; w < n; ++w) {
        const int S = n - w, Sp2 = S | 1;
        int q4 = (w - 2 + 3) >> 2; if (!(q4 & 1)) ++q4;
        const int K4 = 4 * q4;

        // ---- flag-vector barrier: all chunks at width >= w-1 ----
        if (w >= 2) {
            if (tid < 64) {
                const unsigned tgt = (unsigned)(w - 1);
                for (;;) {
                    unsigned f = (tid < 20) ? gloadu(&flags[b * 32 + tid]) : tgt;
                    if (__ballot(f < tgt) == 0ull) break;
                    __builtin_amdgcn_s_sleep(2);
                }
            }
            __syncthreads();
        }

        const bool active = (w == 1) ? (ch < 16) : (ch < 16 || w >= 3);
        int quad, cc0;
        if (w == 1)      { quad = 0; cc0 = ch * 256; }
        else if (ch < 8) { quad = 1; cc0 = ch * 256; }
        else if (ch < 16){ quad = 2; cc0 = (ch - 8) * 256; }
        else             { quad = 3; cc0 = (ch - 16) * 256; }

        // ---- phase A: finalize prev width + NN ELK copies ----
        if (w >= 2) {
            const int wp = w - 1;
            const int tot = (S + 1) * 32;
            const float* pb = ((w & 1) ? partA : partB) + (size_t)b * (20 * 864);
            int e = tid;
            if (e < tot) {
                float q[20];
                #pragma unroll
                for (int c = 0; c < 20; ++c) q[c] = gload(&pb[c * 864 + e]);
                float t = (((q[0] + q[1]) + (q[2] + q[3])) + ((q[4] + q[5]) + (q[6] + q[7])))
                        + (((q[8] + q[9]) + (q[10] + q[11])) + ((q[12] + q[13]) + (q[14] + q[15])))
                        + ((q[16] + q[17]) + (q[18] + q[19]));
                int s = e >> 5, aa = e & 31;
                float t2 = t * lds[O_EMR + aa];
                float m2 = t2;
                for (int off = 16; off > 0; off >>= 1)
                    m2 = fmaxf(m2, __shfl_xor(m2, off, 32));
                float eB = t2 / m2;
                lds[O_BW1 + aa * 30 + s] = eB;
                if (ch >= 16)
                    lds[O_TRI + (off32(wp, n) + s) * 32 + aa] = eB;
                if (aa == 0)
                    lds[O_BMX + wp * NMAX + s] = __logf(m2) + lds[O_MSP + s];
            }
            if (ch >= 16 && w >= 3) {
                int idx = tid;
                if (idx < S * 32) {
                    int s = idx >> 5, sym = idx & 31;
                    int off = (sym * Sp2 + s) * K4;
                    for (int kk = 1; kk <= w - 2; ++kk)
                        lds[O_ELK + off + kk - 1] =
                            lds[O_TRI + (off32(kk, n) + s) * 32 + sym];
                    for (int k = w - 2; k < K4; ++k)
                        lds[O_ELK + off + k] = 0.f;
                }
            }
        }
        __syncthreads();

        // ---- phase B: Mspan + gtab[k][s] ----
        {
            int idx = tid;
            if (idx < w * 32) {
                int k = idx >> 5, s = idx & 31;
                if (s < S) {
                    float M = -3.0e38f;
                    for (int k2 = 0; k2 < w; ++k2)
                        M = fmaxf(M, lds[O_BMX + k2 * NMAX + s] +
                                      lds[O_BMX + (w - 1 - k2) * NMAX + s + k2 + 1]);
                    lds[O_G + k * NMAX + s] =
                        __expf(lds[O_BMX + k * NMAX + s] +
                               lds[O_BMX + (w - 1 - k) * NMAX + s + k + 1] - M);
                    if (k == 0) lds[O_MSP + s] = M;
                }
            }
        }
        __syncthreads();

        // ---- phase B2 (NN only): ERK = TRI * gtab ----
        if (w >= 3 && ch >= 16) {
            int idx = tid;
            if (idx < S * 32) {
                int s = idx >> 5, sym = idx & 31;
                int off = (sym * Sp2 + s) * K4;
                for (int kk = 1; kk <= w - 2; ++kk)
                    lds[O_ERK + off + kk - 1] =
                        lds[O_TRI + (off32(w - 1 - kk, n) + s + kk + 1) * 32 + sym] *
                        lds[O_G + kk * NMAX + s];
            }
            __syncthreads();   // block-uniform (ch uniform per block)
        }

        // ---- phase C: numer build -> bf16 LDS ----
        if (active) {
            const int cL = tid & 255, sh = tid >> 8;   // sh: 0..3
            const int cc = cc0 + cL;
            int l, r;
            if (quad == 0 || quad == 2) { l = cc >> 6; r = cc & 63; }
            else                        { l = cc >> 5; r = cc & 31; }
            unsigned short* np = (unsigned short*)(lds + O_NUM);
            for (int s = sh; s < S; s += 4) {
                float v;
                if (quad == 0)
                    v = lds[O_ELT + l * 29 + s] * lds[O_ELT + r * 29 + (s + 1)] *
                        lds[O_G + s];
                else if (quad == 1)
                    v = lds[O_ELT + l * 29 + s] * lds[O_BW1 + r * 30 + (s + 1)] *
                        lds[O_G + s];
                else if (quad == 2)
                    v = lds[O_BW1 + l * 30 + s] * lds[O_ELT + r * 29 + (s + w)] *
                        lds[O_G + (w - 1) * NMAX + s];
                else {
                    const float* elp = lds + O_ELK + (l * Sp2 + s) * K4;
                    const float* erp = lds + O_ERK + (r * Sp2 + s) * K4;
                    float acc = 0.f;
                    for (int j = 0; j < K4; j += 4)
                        acc = dot4acc(*(const float4*)(elp + j),
                                      *(const float4*)(erp + j), acc);
                    v = acc;
                }
                unsigned u = __float_as_uint(v);
                np[s * 264 + cL] = (unsigned short)((u + 0x7fffu + ((u >> 16) & 1u)) >> 16);
            }
        }
        __syncthreads();

        // ---- phase D: contraction (8 cols/thread, wave-pair reduce) ----
        if (active) {
            const char* nbase = (const char*)(lds + O_NUM);
            const int g32 = tid >> 5, wv = tid >> 6;
            const bool lowhalf = (tid & 32) == 0;
            for (int s = 0; s < S; ++s) {
                uint4 u = *(const uint4*)(nbase + s * 528 + g32 * 16);
                float acc = 0.f;
                #define LO(q) __uint_as_float((q) << 16)
                #define HI(q) __uint_as_float((q) & 0xffff0000u)
                acc = fmaf(LO(u.x), e4[0].x, acc); acc = fmaf(HI(u.x), e4[0].y, acc);
                acc = fmaf(LO(u.y), e4[0].z, acc); acc = fmaf(HI(u.y), e4[0].w, acc);
                acc = fmaf(LO(u.z), e4[1].x, acc); acc = fmaf(HI(u.z), e4[1].y, acc);
                acc = fmaf(LO(u.w), e4[1].z, acc); acc = fmaf(HI(u.w), e4[1].w, acc);
                #undef LO
                #undef HI
                acc += __shfl_xor(acc, 32, 64);
                if (lowhalf) lds[O_RED + wv * 896 + s * 32 + a] = acc;
            }
        }
        __syncthreads();

        // ---- phase E: 16-group reduce -> uncached chunk partials ----
        {
            float* pb = ((w & 1) ? partB : partA) + (size_t)b * (20 * 864);
            int e = tid;
            if (e < S * 32) {
                float t = 0.f;
                if (active) {
                    #pragma unroll
                    for (int g2 = 0; g2 < 16; ++g2)
                        t += lds[O_RED + g2 * 896 + e];
                }
                gstore(&pb[ch * 864 + e], t);
            }
        }
        __syncthreads();   // drains vmcnt -> partial stores globally visible

        if (tid == 0) gstoreu(&flags[b * 32 + ch], (unsigned)w);

        // switch ch<16 blocks from TT role to TN/NT role after width 1
        if (w == 1 && ch < 16) {
            const float4* Eq = (ch < 8)
                ? (const float4*)E_TN + (size_t)b * 16384 + (size_t)(ch * 64) * 32
                : (const float4*)E_NT + (size_t)b * 16384 + (size_t)((ch - 8) * 64) * 32;
            #pragma unroll
            for (int i = 0; i < 2; ++i)
                e4[i] = Eq[(size_t)((tid >> 5) * 2 + i) * 32 + a];
        }
    }

    // ---- epilogue (ch==0): finalize width n-1 span 0 + root logsumexp ----
    if (ch == 0) {
        if (tid < 64) {
            const unsigned tgt = (unsigned)(n - 1);
            for (;;) {
                unsigned f = (tid < 20) ? gloadu(&flags[b * 32 + tid]) : tgt;
                if (__ballot(f < tgt) == 0ull) break;
                __builtin_amdgcn_s_sleep(2);
            }
        }
        __syncthreads();
        if (tid < 32) {
            const float* pb = (((n - 1) & 1) ? partB : partA) + (size_t)b * (20 * 864);
            float q[20];
            #pragma unroll
            for (int c = 0; c < 20; ++c) q[c] = gload(&pb[c * 864 + tid]);
            float t = (((q[0] + q[1]) + (q[2] + q[3])) + ((q[4] + q[5]) + (q[6] + q[7])))
                    + (((q[8] + q[9]) + (q[10] + q[11])) + ((q[12] + q[13]) + (q[14] + q[15])))
                    + ((q[16] + q[17]) + (q[18] + q[19]));
            float v = __logf(t) + lds[O_MSP + 0] + mrule[b * 32 + tid] + root[b * 32 + tid];
            float m = v;
            for (int off = 16; off > 0; off >>= 1) m = fmaxf(m, __shfl_xor(m, off, 32));
            float e = __expf(v - m);
            for (int off = 16; off > 0; off >>= 1) e += __shfl_xor(e, off, 32);
            if (tid == 0) out[b] = m + __logf(e);
        }
    }
}

extern "C" void kernel_launch(void* const* d_in, const int* in_sizes, int n_in,
                              void* d_out, int out_size, void* d_ws, size_t ws_size,
                              hipStream_t stream) {
    const float* unary = (const float*)d_in[0]; // B,n,64
    const float* rule  = (const float*)d_in[1]; // B,32,96,96
    const float* root  = (const float*)d_in[2]; // B,32
    float* out = (float*)d_out;

    const int B = in_sizes[2] / 32;
    int n = in_sizes[0] / (B * 64);

    float* ws = (float*)d_ws;
    float* mrule  = ws;                               // B*32
    float* E_TT   = mrule + (size_t)B * 32;           // B*1024*32*4
    float* E_TN   = E_TT + (size_t)B * 131072;        // B*512*32*4
    float* E_NT   = E_TN + (size_t)B * 65536;         // B*512*32*4
    float* E_NN   = E_NT + (size_t)B * 65536;         // B*256*32*4
    float* partA  = E_NN + (size_t)B * 32768;         // B*20*864
    float* partB  = partA + (size_t)B * 20 * 864;
    unsigned* flags = (unsigned*)(partB + (size_t)B * 20 * 864); // B*32

    mrule_kernel<<<dim3(32, B), 256, 0, stream>>>(rule, mrule, flags);
    pack_kernel<<<dim3(288, B), 256, 0, stream>>>(rule, mrule, E_TT, E_TN, E_NT, E_NN);

    hipFuncSetAttribute((const void*)inside_kernel,
                        hipFuncAttributeMaxDynamicSharedMemorySize, LDSF * 4);

    void* args[] = {
        (void*)&unary, (void*)&mrule,
        (void*)&E_TT, (void*)&E_TN, (void*)&E_NT, (void*)&E_NN,
        (void*)&partA, (void*)&partB, (void*)&root,
        (void*)&out, (void*)&flags, (void*)&n
    };
    hipLaunchCooperativeKernel((void*)inside_kernel, dim3(B * 20), dim3(1024),
                               args, LDSF * 4, stream);
}

// Round 12
// 242.676 us; speedup vs baseline: 2.7543x; 1.1040x over previous
//
#include <hip/hip_runtime.h>
#include <cstdint>
#include <cstddef>

// PCFG inside algorithm. B=8, n=28, NT=32, T=64, ST=96.
// Persistent cooperative kernel v4 -- NN-decoupled software pipeline.
// Grid = B*20 blocks, 1024 threads. Block (b,ch) owns 256 pair-columns of
// packed erule in REGS (2 float4/thr).
// TNT blocks (ch<16: TT at w==1, TN ch0-7 / NT ch8-15 after): wait flags
// >= w-1, finalize width w-1 (20 fully-unrolled uncached loads, NN part
// rescaled by exp(M'-M)), compute M/g0/gw, numer (single mul), contract,
// store partials, publish flag=w.
// NN blocks (ch16-19, widths w>=3): wait flags >= w-2 ONLY (rows <= w-2
// suffice; own normalization M' = max over k=1..w-2), finalize width w-2
// into a private LDS eB triangle, build k-packed ELK/ERK, dot, contract,
// store partials + M' row, publish flag=w. Runs ~1.5 rounds ahead; its
// whole chain overlaps two TNT rounds.
// Partials: 4-slot ring (monotone flags make slot reuse WAR-safe). Slot
// layout: 20*864 partials | M row (32) | M' row (32). All cross-block data
// via agent-scope (uncached) atomics; no L2 flushes anywhere.

#define NMAX 28
#define SLOT 17344
#define MROW 17280
#define MPROW 17312

// LDS float offsets
#define O_BW1 0        // 32*30: eB row w-1 [sym][s] (TNT)
#define O_BMX 960      // 28*28: bmax triangle [lvl][pos] (persistent)
#define O_G   1744     // 28*28: TNT: rows 0,1 = g0,gw ; NN: g'[k][s]
#define O_MSP 2528     // 32: TNT Mspan (persists into next finalize)
#define O_EMR 2560     // 32: exp(mrule)
#define O_NUM 2592     // ushort numer: 27 spans * 264 (528B pitch)
#define O_RED 6160     // 14336: red[wv16][s*32+a]
// TNT only:
#define O_ELT 20496    // 64*29: elT[t][pos] (persistent)
// NN only (ELK/ERK alias RED region, dead by phase D; ERK tail overlaps ELT):
#define O_ELK 6160     // 8320
#define O_ERK 14480    // 8320
#define O_TRI 22800    // 12064: eB triangle rows 1..n-2, [off32(w)+s][sym]
#define LDSF  34864    // *4 = 139456 B

__device__ __forceinline__ int off32(int w, int n) {
    return (w - 1) * n - (w * (w - 1)) / 2;
}
__device__ __forceinline__ float gload(const float* p) {
    return __hip_atomic_load(p, __ATOMIC_RELAXED, __HIP_MEMORY_SCOPE_AGENT);
}
__device__ __forceinline__ void gstore(float* p, float v) {
    __hip_atomic_store(p, v, __ATOMIC_RELAXED, __HIP_MEMORY_SCOPE_AGENT);
}
__device__ __forceinline__ unsigned gloadu(const unsigned* p) {
    return __hip_atomic_load(p, __ATOMIC_RELAXED, __HIP_MEMORY_SCOPE_AGENT);
}
__device__ __forceinline__ void gstoreu(unsigned* p, unsigned v) {
    __hip_atomic_store(p, v, __ATOMIC_RELAXED, __HIP_MEMORY_SCOPE_AGENT);
}
__device__ __forceinline__ float dot4acc(float4 m, float4 t, float acc) {
    return fmaf(m.x, t.x, fmaf(m.y, t.y, fmaf(m.z, t.z, fmaf(m.w, t.w, acc))));
}

__global__ __launch_bounds__(256) void mrule_kernel(const float* __restrict__ rule,
                                                    float* __restrict__ mrule,
                                                    unsigned* __restrict__ flags) {
    int a = blockIdx.x, b = blockIdx.y, tid = threadIdx.x;
    // NN flags start at 2: widths 1,2 have no NN work.
    if (a == 0 && tid < 32)
        gstoreu(&flags[b * 32 + tid], (tid >= 16 && tid < 20) ? 2u : 0u);
    const float* base = rule + (size_t)(b * 32 + a) * 9216;
    float v = -3.0e38f;
    for (int i = tid; i < 9216; i += 256) v = fmaxf(v, base[i]);
    for (int off = 32; off > 0; off >>= 1) v = fmaxf(v, __shfl_xor(v, off, 64));
    __shared__ float red[4];
    if ((tid & 63) == 0) red[tid >> 6] = v;
    __syncthreads();
    if (tid == 0)
        mrule[b * 32 + a] = fmaxf(fmaxf(red[0], red[1]), fmaxf(red[2], red[3]));
}

__global__ __launch_bounds__(256) void pack_kernel(const float* __restrict__ rule,
                                                   const float* __restrict__ mrule,
                                                   float* __restrict__ E_TT,
                                                   float* __restrict__ E_TN,
                                                   float* __restrict__ E_NT,
                                                   float* __restrict__ E_NN) {
    int b = blockIdx.y, tid = threadIdx.x;
    int a = tid & 31;
    int cc = blockIdx.x * 8 + (tid >> 5); // 0..2303
    float mr = mrule[b * 32 + a];
    int l, r;
    float* dst;
    if (cc < 1024) {
        int flat = cc * 4;
        l = 32 + (flat >> 6); r = 32 + (flat & 63);
        dst = E_TT + ((size_t)(b * 1024 + cc) * 32 + a) * 4;
    } else if (cc < 1536) {
        int flat = (cc - 1024) * 4;
        l = 32 + (flat >> 5); r = flat & 31;
        dst = E_TN + ((size_t)(b * 512 + (cc - 1024)) * 32 + a) * 4;
    } else if (cc < 2048) {
        int flat = (cc - 1536) * 4;
        l = flat >> 6; r = 32 + (flat & 63);
        dst = E_NT + ((size_t)(b * 512 + (cc - 1536)) * 32 + a) * 4;
    } else {
        int flat = (cc - 2048) * 4;
        l = flat >> 5; r = flat & 31;
        dst = E_NN + ((size_t)(b * 256 + (cc - 2048)) * 32 + a) * 4;
    }
    const float4 v = *(const float4*)(rule + (((size_t)(b * 32 + a) * 96 + l) * 96 + r));
    float4 o;
    o.x = expf(v.x - mr); o.y = expf(v.y - mr);
    o.z = expf(v.z - mr); o.w = expf(v.w - mr);
    *(float4*)dst = o;
}

__device__ __forceinline__ void spin_flags(const unsigned* f, unsigned tgt, int tid) {
    if (tid < 64) {
        for (;;) {
            unsigned v = (tid < 20) ? gloadu(&f[tid]) : tgt;
            if (__ballot(v < tgt) == 0ull) break;
            __builtin_amdgcn_s_sleep(2);
        }
    }
    __syncthreads();
}

__global__ __launch_bounds__(1024, 4) void inside_kernel(
    const float* __restrict__ unary, const float* __restrict__ mrule,
    const float* __restrict__ E_TT, const float* __restrict__ E_TN,
    const float* __restrict__ E_NT, const float* __restrict__ E_NN,
    float* __restrict__ part, const float* __restrict__ root,
    float* __restrict__ out, unsigned* __restrict__ flags, int n) {
    extern __shared__ float lds[];
    const int b = blockIdx.x / 20, ch = blockIdx.x % 20;
    const int tid = threadIdx.x;
    const int a = tid & 31;
    unsigned* const myflags = flags + b * 32;
    float* const pbase = part + (size_t)(b * 4) * SLOT;

    // ---- prologue ----
    float4 e4[2];
    {
        const float4* Eq;
        int base4;
        if (ch < 16) { Eq = (const float4*)E_TT + (size_t)b * 32768; base4 = ch * 64; }
        else         { Eq = (const float4*)E_NN + (size_t)b * 8192;  base4 = (ch - 16) * 64; }
        #pragma unroll
        for (int i = 0; i < 2; ++i)
            e4[i] = Eq[(size_t)(base4 + (tid >> 5) * 2 + i) * 32 + a];
    }
    if (tid < 32) lds[O_EMR + tid] = __expf(mrule[b * 32 + tid]);
    for (int pos = tid >> 6; pos < n; pos += 16) {
        int t = tid & 63;
        float v = unary[((size_t)b * n + pos) * 64 + t];
        float m = v;
        for (int off = 32; off > 0; off >>= 1) m = fmaxf(m, __shfl_xor(m, off, 64));
        if (t == 0) lds[O_BMX + pos] = m;
        if (ch < 16) lds[O_ELT + t * 29 + pos] = __expf(v - m);
    }
    __syncthreads();

    if (ch < 16) {
        // ================= TNT role =================
        for (int w = 1; w < n; ++w) {
            const int S = n - w;
            float* pbW = pbase + (size_t)(w & 3) * SLOT;

            if (w >= 2) {
                spin_flags(myflags, (unsigned)(w - 1), tid);
                // phase A: finalize width w-1
                const int wp = w - 1;
                const float* pbP = pbase + (size_t)(wp & 3) * SLOT;
                if (tid < (S + 1) * 32) {
                    int s = tid >> 5, aa = tid & 31;
                    float q[20];
                    #pragma unroll
                    for (int c = 0; c < 20; ++c) q[c] = gload(&pbP[c * 864 + tid]);
                    float tT = (((q[0] + q[1]) + (q[2] + q[3])) + ((q[4] + q[5]) + (q[6] + q[7])))
                             + (((q[8] + q[9]) + (q[10] + q[11])) + ((q[12] + q[13]) + (q[14] + q[15])));
                    float t = tT;
                    if (wp >= 3) {
                        float tN = (q[16] + q[17]) + (q[18] + q[19]);
                        float Mp = gload(&pbP[MPROW + s]);
                        t = fmaf(__expf(Mp - lds[O_MSP + s]), tN, tT);
                    }
                    float t2 = t * lds[O_EMR + aa];
                    float m2 = t2;
                    for (int off = 16; off > 0; off >>= 1)
                        m2 = fmaxf(m2, __shfl_xor(m2, off, 32));
                    lds[O_BW1 + aa * 30 + s] = t2 / m2;
                    if (aa == 0)
                        lds[O_BMX + wp * NMAX + s] = __logf(m2) + lds[O_MSP + s];
                }
                __syncthreads();
            }

            // phase B: M, g0, gw (+ ch0 publishes M row)
            if (tid < S) {
                int s = tid;
                float M = -3.0e38f;
                for (int k = 0; k < w; ++k)
                    M = fmaxf(M, lds[O_BMX + k * NMAX + s] +
                                  lds[O_BMX + (w - 1 - k) * NMAX + s + k + 1]);
                lds[O_MSP + s] = M;
                lds[O_G + s] =
                    __expf(lds[O_BMX + s] + lds[O_BMX + (w - 1) * NMAX + s + 1] - M);
                lds[O_G + NMAX + s] =
                    __expf(lds[O_BMX + (w - 1) * NMAX + s] + lds[O_BMX + s + w] - M);
                if (ch == 0) gstore(&pbW[MROW + s], M);
            }
            __syncthreads();

            // phase C: numer -> bf16 LDS (single mul path)
            {
                const int cL = tid & 255, sh = tid >> 8;
                const bool tn = (w >= 2) && (ch < 8);
                const int cc = (w == 1) ? ch * 256 + cL
                             : (ch < 8 ? ch * 256 + cL : (ch - 8) * 256 + cL);
                int l, r;
                if (tn) { l = cc >> 5; r = cc & 31; }
                else    { l = cc >> 6; r = cc & 63; }
                unsigned short* np = (unsigned short*)(lds + O_NUM);
                for (int s = sh; s < S; s += 4) {
                    float v;
                    if (w == 1)
                        v = lds[O_ELT + l * 29 + s] * lds[O_ELT + r * 29 + (s + 1)] *
                            lds[O_G + s];
                    else if (tn)
                        v = lds[O_ELT + l * 29 + s] * lds[O_BW1 + r * 30 + (s + 1)] *
                            lds[O_G + s];
                    else
                        v = lds[O_BW1 + l * 30 + s] * lds[O_ELT + r * 29 + (s + w)] *
                            lds[O_G + NMAX + s];
                    unsigned u = __float_as_uint(v);
                    np[s * 264 + cL] = (unsigned short)((u + 0x7fffu + ((u >> 16) & 1u)) >> 16);
                }
            }
            __syncthreads();

            // phase D: contraction
            {
                const char* nbase = (const char*)(lds + O_NUM);
                const int g32 = tid >> 5, wv = tid >> 6;
                const bool lowhalf = (tid & 32) == 0;
                for (int s = 0; s < S; ++s) {
                    uint4 u = *(const uint4*)(nbase + s * 528 + g32 * 16);
                    float acc = 0.f;
                    #define LO(q) __uint_as_float((q) << 16)
                    #define HI(q) __uint_as_float((q) & 0xffff0000u)
                    acc = fmaf(LO(u.x), e4[0].x, acc); acc = fmaf(HI(u.x), e4[0].y, acc);
                    acc = fmaf(LO(u.y), e4[0].z, acc); acc = fmaf(HI(u.y), e4[0].w, acc);
                    acc = fmaf(LO(u.z), e4[1].x, acc); acc = fmaf(HI(u.z), e4[1].y, acc);
                    acc = fmaf(LO(u.w), e4[1].z, acc); acc = fmaf(HI(u.w), e4[1].w, acc);
                    #undef LO
                    #undef HI
                    acc += __shfl_xor(acc, 32, 64);
                    if (lowhalf) lds[O_RED + wv * 896 + s * 32 + a] = acc;
                }
            }
            __syncthreads();

            // phase E
            if (tid < S * 32) {
                float t = 0.f;
                #pragma unroll
                for (int g2 = 0; g2 < 16; ++g2) t += lds[O_RED + g2 * 896 + tid];
                gstore(&pbW[ch * 864 + tid], t);
            }
            __syncthreads();
            if (tid == 0) gstoreu(&myflags[ch], (unsigned)w);

            if (w == 1) {
                const float4* Eq = (ch < 8)
                    ? (const float4*)E_TN + (size_t)b * 16384 + (size_t)(ch * 64) * 32
                    : (const float4*)E_NT + (size_t)b * 16384 + (size_t)((ch - 8) * 64) * 32;
                #pragma unroll
                for (int i = 0; i < 2; ++i)
                    e4[i] = Eq[(size_t)((tid >> 5) * 2 + i) * 32 + a];
            }
        }

        // epilogue (ch==0): width n-1, span 0 + root logsumexp
        if (ch == 0) {
            spin_flags(myflags, (unsigned)(n - 1), tid);
            if (tid < 32) {
                const float* pbP = pbase + (size_t)((n - 1) & 3) * SLOT;
                float q[20];
                #pragma unroll
                for (int c = 0; c < 20; ++c) q[c] = gload(&pbP[c * 864 + tid]);
                float tT = (((q[0] + q[1]) + (q[2] + q[3])) + ((q[4] + q[5]) + (q[6] + q[7])))
                         + (((q[8] + q[9]) + (q[10] + q[11])) + ((q[12] + q[13]) + (q[14] + q[15])));
                float tN = (q[16] + q[17]) + (q[18] + q[19]);
                float Mp = gload(&pbP[MPROW + 0]);
                float t = fmaf(__expf(Mp - lds[O_MSP + 0]), tN, tT);
                float v = __logf(t) + lds[O_MSP + 0] + mrule[b * 32 + tid] + root[b * 32 + tid];
                float m = v;
                for (int off = 16; off > 0; off >>= 1) m = fmaxf(m, __shfl_xor(m, off, 32));
                float e = __expf(v - m);
                for (int off = 16; off > 0; off >>= 1) e += __shfl_xor(e, off, 32);
                if (tid == 0) out[b] = m + __logf(e);
            }
        }
    } else {
        // ================= NN role (runs ahead) =================
        for (int w = 3; w < n; ++w) {
            const int S = n - w, Sp2 = S | 1;
            int q4 = (w - 2 + 3) >> 2; if (!(q4 & 1)) ++q4;
            const int K4 = 4 * q4;
            float* pbW = pbase + (size_t)(w & 3) * SLOT;

            spin_flags(myflags, (unsigned)(w - 2), tid);

            // A1: finalize width w-2 into TRI + bmax row
            {
                const int wf = w - 2;
                const float* pbF = pbase + (size_t)(wf & 3) * SLOT;
                if (tid < (n - wf) * 32) {
                    int s = tid >> 5, aa = tid & 31;
                    float q[20];
                    #pragma unroll
                    for (int c = 0; c < 20; ++c) q[c] = gload(&pbF[c * 864 + tid]);
                    float tT = (((q[0] + q[1]) + (q[2] + q[3])) + ((q[4] + q[5]) + (q[6] + q[7])))
                             + (((q[8] + q[9]) + (q[10] + q[11])) + ((q[12] + q[13]) + (q[14] + q[15])));
                    float Mf = gload(&pbF[MROW + s]);
                    float t = tT;
                    if (wf >= 3) {
                        float tN = (q[16] + q[17]) + (q[18] + q[19]);
                        float Mp = gload(&pbF[MPROW + s]);
                        t = fmaf(__expf(Mp - Mf), tN, tT);
                    }
                    float t2 = t * lds[O_EMR + aa];
                    float m2 = t2;
                    for (int off = 16; off > 0; off >>= 1)
                        m2 = fmaxf(m2, __shfl_xor(m2, off, 32));
                    lds[O_TRI + (off32(wf, n) + s) * 32 + aa] = t2 / m2;
                    if (aa == 0) lds[O_BMX + wf * NMAX + s] = __logf(m2) + Mf;
                }
                __syncthreads();
            }

            // A2: M' (max over k=1..w-2) + g'[k][s]; ch16 publishes M' row
            if (tid < (w - 2) * 32) {
                int k = (tid >> 5) + 1, s = tid & 31;
                if (s < S) {
                    float Mp = -3.0e38f;
                    for (int k2 = 1; k2 <= w - 2; ++k2)
                        Mp = fmaxf(Mp, lds[O_BMX + k2 * NMAX + s] +
                                       lds[O_BMX + (w - 1 - k2) * NMAX + s + k2 + 1]);
                    lds[O_G + k * NMAX + s] =
                        __expf(lds[O_BMX + k * NMAX + s] +
                               lds[O_BMX + (w - 1 - k) * NMAX + s + k + 1] - Mp);
                    if (k == 1 && ch == 16) gstore(&pbW[MPROW + s], Mp);
                }
            }
            __syncthreads();

            // A3: k-packed ELK/ERK from LDS triangle (g' folded into ERK)
            if (tid < S * 32) {
                int s = tid >> 5, sym = tid & 31;
                int off = (sym * Sp2 + s) * K4;
                for (int kk = 1; kk <= w - 2; ++kk) {
                    lds[O_ELK + off + kk - 1] =
                        lds[O_TRI + (off32(kk, n) + s) * 32 + sym];
                    lds[O_ERK + off + kk - 1] =
                        lds[O_TRI + (off32(w - 1 - kk, n) + s + kk + 1) * 32 + sym] *
                        lds[O_G + kk * NMAX + s];
                }
                for (int k = w - 2; k < K4; ++k) {
                    lds[O_ELK + off + k] = 0.f;
                    lds[O_ERK + off + k] = 0.f;
                }
            }
            __syncthreads();

            // C: numer (K4 dot) -> bf16 LDS
            {
                const int cL = tid & 255, sh = tid >> 8;
                const int cc = (ch - 16) * 256 + cL;
                const int l = cc >> 5, r = cc & 31;
                unsigned short* np = (unsigned short*)(lds + O_NUM);
                for (int s = sh; s < S; s += 4) {
                    const float* elp = lds + O_ELK + (l * Sp2 + s) * K4;
                    const float* erp = lds + O_ERK + (r * Sp2 + s) * K4;
                    float acc = 0.f;
                    for (int j = 0; j < K4; j += 4)
                        acc = dot4acc(*(const float4*)(elp + j),
                                      *(const float4*)(erp + j), acc);
                    unsigned u = __float_as_uint(acc);
                    np[s * 264 + cL] = (unsigned short)((u + 0x7fffu + ((u >> 16) & 1u)) >> 16);
                }
            }
            __syncthreads();

            // D: contraction
            {
                const char* nbase = (const char*)(lds + O_NUM);
                const int g32 = tid >> 5, wv = tid >> 6;
                const bool lowhalf = (tid & 32) == 0;
                for (int s = 0; s < S; ++s) {
                    uint4 u = *(const uint4*)(nbase + s * 528 + g32 * 16);
                    float acc = 0.f;
                    #define LO(q) __uint_as_float((q) << 16)
                    #define HI(q) __uint_as_float((q) & 0xffff0000u)
                    acc = fmaf(LO(u.x), e4[0].x, acc); acc = fmaf(HI(u.x), e4[0].y, acc);
                    acc = fmaf(LO(u.y), e4[0].z, acc); acc = fmaf(HI(u.y), e4[0].w, acc);
                    acc = fmaf(LO(u.z), e4[1].x, acc); acc = fmaf(HI(u.z), e4[1].y, acc);
                    acc = fmaf(LO(u.w), e4[1].z, acc); acc = fmaf(HI(u.w), e4[1].w, acc);
                    #undef LO
                    #undef HI
                    acc += __shfl_xor(acc, 32, 64);
                    if (lowhalf) lds[O_RED + wv * 896 + s * 32 + a] = acc;
                }
            }
            __syncthreads();

            // E
            if (tid < S * 32) {
                float t = 0.f;
                #pragma unroll
                for (int g2 = 0; g2 < 16; ++g2) t += lds[O_RED + g2 * 896 + tid];
                gstore(&pbW[ch * 864 + tid], t);
            }
            __syncthreads();
            if (tid == 0) gstoreu(&myflags[ch], (unsigned)w);
        }
    }
}

extern "C" void kernel_launch(void* const* d_in, const int* in_sizes, int n_in,
                              void* d_out, int out_size, void* d_ws, size_t ws_size,
                              hipStream_t stream) {
    const float* unary = (const float*)d_in[0]; // B,n,64
    const float* rule  = (const float*)d_in[1]; // B,32,96,96
    const float* root  = (const float*)d_in[2]; // B,32
    float* out = (float*)d_out;

    const int B = in_sizes[2] / 32;
    int n = in_sizes[0] / (B * 64);

    float* ws = (float*)d_ws;
    float* mrule  = ws;                               // B*32
    float* E_TT   = mrule + (size_t)B * 32;           // B*1024*32*4
    float* E_TN   = E_TT + (size_t)B * 131072;        // B*512*32*4
    float* E_NT   = E_TN + (size_t)B * 65536;         // B*512*32*4
    float* E_NN   = E_NT + (size_t)B * 65536;         // B*256*32*4
    float* part   = E_NN + (size_t)B * 32768;         // B*4*SLOT
    unsigned* flags = (unsigned*)(part + (size_t)B * 4 * SLOT); // B*32

    mrule_kernel<<<dim3(32, B), 256, 0, stream>>>(rule, mrule, flags);
    pack_kernel<<<dim3(288, B), 256, 0, stream>>>(rule, mrule, E_TT, E_TN, E_NT, E_NN);

    hipFuncSetAttribute((const void*)inside_kernel,
                        hipFuncAttributeMaxDynamicSharedMemorySize, LDSF * 4);

    void* args[] = {
        (void*)&unary, (void*)&mrule,
        (void*)&E_TT, (void*)&E_TN, (void*)&E_NT, (void*)&E_NN,
        (void*)&part, (void*)&root, (void*)&out, (void*)&flags, (void*)&n
    };
    hipLaunchCooperativeKernel((void*)inside_kernel, dim3(B * 20), dim3(1024),
                               args, LDSF * 4, stream);
}